// Round 2
// baseline (663.306 us; speedup 1.0000x reference)
//
#include <hip/hip_runtime.h>
#include <stdint.h>

typedef short bf16x8 __attribute__((ext_vector_type(8)));
typedef short bf16x4 __attribute__((ext_vector_type(4)));
typedef float f32x4 __attribute__((ext_vector_type(4)));

__device__ __forceinline__ short f2bf(float f) {
  union { float f; uint32_t u; } v; v.f = f;
  uint32_t r = (v.u + 0x7FFFu + ((v.u >> 16) & 1u)) >> 16;
  return (short)(uint16_t)r;
}

// ---------------- elementwise f32 -> bf16 ----------------
__global__ __launch_bounds__(256) void k_convert(const float* __restrict__ in,
                                                 short* __restrict__ out, int n) {
  int i = (blockIdx.x * 256 + threadIdx.x) * 4;
  if (i >= n) return;
  float4 v = *reinterpret_cast<const float4*>(in + i);
  bf16x4 o; o[0] = f2bf(v.x); o[1] = f2bf(v.y); o[2] = f2bf(v.z); o[3] = f2bf(v.w);
  *reinterpret_cast<bf16x4*>(out + i) = o;
}

// ---------------- transpose + convert: out[C][R] = bf16(in[R][C]) ----------------
__global__ __launch_bounds__(256) void k_transpose_cvt(const float* __restrict__ in,
                                                       short* __restrict__ out,
                                                       int R, int C) {
  __shared__ float tile[32][33];
  int r0 = blockIdx.y * 32, c0 = blockIdx.x * 32;
  int tx = threadIdx.x & 31, ty = threadIdx.x >> 5;
#pragma unroll
  for (int j = 0; j < 4; ++j)
    tile[ty + j * 8][tx] = in[(size_t)(r0 + ty + j * 8) * C + c0 + tx];
  __syncthreads();
#pragma unroll
  for (int j = 0; j < 4; ++j)
    out[(size_t)(c0 + ty + j * 8) * R + r0 + tx] = f2bf(tile[tx][ty + j * 8]);
}

// ---------------- GEMM1: qkv = x @ W_attn + b ----------------
__global__ __launch_bounds__(256) void k_gemm_qkv(const short* __restrict__ A,
                                                  const short* __restrict__ BT,
                                                  const float* __restrict__ bias,
                                                  short* __restrict__ C) {
  __shared__ short As[128][40];
  __shared__ short Bs[128][40];
  const int tid = threadIdx.x, lane = tid & 63, w = tid >> 6;
  const int wm = w >> 1, wn = w & 1;
  const int r16 = lane & 15, g4 = lane >> 4;
  const int m0 = blockIdx.x * 128, n0 = blockIdx.y * 128;
  f32x4 acc[4][4];
#pragma unroll
  for (int i = 0; i < 4; ++i)
#pragma unroll
    for (int j = 0; j < 4; ++j) acc[i][j] = f32x4{0.f, 0.f, 0.f, 0.f};
  for (int k0 = 0; k0 < 1024; k0 += 32) {
#pragma unroll
    for (int it = 0; it < 2; ++it) {
      int slot = tid + it * 256;
      int row = slot >> 2, dg = slot & 3;
      *reinterpret_cast<bf16x8*>(&As[row][dg * 8]) =
          *reinterpret_cast<const bf16x8*>(&A[(size_t)(m0 + row) * 1024 + k0 + dg * 8]);
      *reinterpret_cast<bf16x8*>(&Bs[row][dg * 8]) =
          *reinterpret_cast<const bf16x8*>(&BT[(size_t)(n0 + row) * 1024 + k0 + dg * 8]);
    }
    __syncthreads();
    bf16x8 af[4], bfr[4];
#pragma unroll
    for (int i = 0; i < 4; ++i)
      af[i] = *reinterpret_cast<const bf16x8*>(&As[wm * 64 + i * 16 + r16][g4 * 8]);
#pragma unroll
    for (int j = 0; j < 4; ++j)
      bfr[j] = *reinterpret_cast<const bf16x8*>(&Bs[wn * 64 + j * 16 + r16][g4 * 8]);
#pragma unroll
    for (int i = 0; i < 4; ++i)
#pragma unroll
      for (int j = 0; j < 4; ++j)
        acc[i][j] = __builtin_amdgcn_mfma_f32_16x16x32_bf16(af[i], bfr[j], acc[i][j], 0, 0, 0);
    __syncthreads();
  }
#pragma unroll
  for (int i = 0; i < 4; ++i)
#pragma unroll
    for (int j = 0; j < 4; ++j) {
      int row = m0 + wm * 64 + i * 16 + g4 * 4;
      int col = n0 + wn * 64 + j * 16 + r16;
      float bv = bias[col];
#pragma unroll
      for (int q = 0; q < 4; ++q)
        C[(size_t)(row + q) * 3072 + col] = f2bf(acc[i][j][q] + bv);
    }
}

// ---------------- Projection ----------------
// K: kp[b][kk][c] = sum_t Et[kk][t]*k[b][t][c] * 1/8   (row-major)
// V: vpt[b][c][kk] = sum_t Ft[kk][t]*v[b][t][c]        (TRANSPOSED for attn PV)
__global__ __launch_bounds__(256) void k_proj(const short* __restrict__ Et,
                                              const short* __restrict__ Ft,
                                              const short* __restrict__ qkv,
                                              short* __restrict__ kp,
                                              short* __restrict__ vpt) {
  const int z = blockIdx.z, b = z >> 1, which = z & 1;
  const short* __restrict__ AT = which ? Ft : Et;
  const int koff = which ? 2048 : 1024;
  __shared__ short As[128][40];
  __shared__ short Bs[128][40];
  const int tid = threadIdx.x, lane = tid & 63, w = tid >> 6;
  const int wm = w >> 1, wn = w & 1;
  const int r16 = lane & 15, g4 = lane >> 4;
  const int m0 = blockIdx.x * 128, n0 = blockIdx.y * 128;
  const int cLane = tid & 127, tHalf = tid >> 7;
  f32x4 acc[4][4];
#pragma unroll
  for (int i = 0; i < 4; ++i)
#pragma unroll
    for (int j = 0; j < 4; ++j) acc[i][j] = f32x4{0.f, 0.f, 0.f, 0.f};
  for (int t0 = 0; t0 < 4096; t0 += 32) {
#pragma unroll
    for (int it = 0; it < 2; ++it) {
      int slot = tid + it * 256;
      int row = slot >> 2, dg = slot & 3;
      *reinterpret_cast<bf16x8*>(&As[row][dg * 8]) =
          *reinterpret_cast<const bf16x8*>(&AT[(size_t)(m0 + row) * 4096 + t0 + dg * 8]);
    }
#pragma unroll
    for (int it = 0; it < 16; ++it) {
      int t = tHalf * 16 + it;
      Bs[cLane][t] = qkv[(size_t)(b * 4096 + t0 + t) * 3072 + koff + n0 + cLane];
    }
    __syncthreads();
    bf16x8 af[4], bfr[4];
#pragma unroll
    for (int i = 0; i < 4; ++i)
      af[i] = *reinterpret_cast<const bf16x8*>(&As[wm * 64 + i * 16 + r16][g4 * 8]);
#pragma unroll
    for (int j = 0; j < 4; ++j)
      bfr[j] = *reinterpret_cast<const bf16x8*>(&Bs[wn * 64 + j * 16 + r16][g4 * 8]);
#pragma unroll
    for (int i = 0; i < 4; ++i)
#pragma unroll
      for (int j = 0; j < 4; ++j)
        acc[i][j] = __builtin_amdgcn_mfma_f32_16x16x32_bf16(af[i], bfr[j], acc[i][j], 0, 0, 0);
    __syncthreads();
  }
  if (which) {
    // transposed store: vpt[b][col][row..row+3]
#pragma unroll
    for (int i = 0; i < 4; ++i)
#pragma unroll
      for (int j = 0; j < 4; ++j) {
        int row = m0 + wm * 64 + i * 16 + g4 * 4;
        int col = n0 + wn * 64 + j * 16 + r16;
        bf16x4 ov;
#pragma unroll
        for (int q = 0; q < 4; ++q) ov[q] = f2bf(acc[i][j][q]);
        *reinterpret_cast<bf16x4*>(&vpt[((size_t)(b * 1024) + col) * 1024 + row]) = ov;
      }
  } else {
#pragma unroll
    for (int i = 0; i < 4; ++i)
#pragma unroll
      for (int j = 0; j < 4; ++j) {
        int row = m0 + wm * 64 + i * 16 + g4 * 4;
        int col = n0 + wn * 64 + j * 16 + r16;
#pragma unroll
        for (int q = 0; q < 4; ++q)
          kp[((size_t)(b * 1024) + row + q) * 1024 + col] = f2bf(acc[i][j][q] * 0.125f);
      }
  }
}

// ---------------- Flash attention: K/V fragments direct from global (L2-resident) --------
__global__ __launch_bounds__(256, 3) void k_attn(const short* __restrict__ qkv,
                                                 const short* __restrict__ kp,
                                                 const short* __restrict__ vpt,
                                                 short* __restrict__ y) {
  __shared__ short P[4][32][72];  // per-wave P-transpose buffer (wave-local, no barriers)
  const int tid = threadIdx.x, lane = tid & 63, w = tid >> 6;
  const int r16 = lane & 15, g4 = lane >> 4;
  const int iblk = blockIdx.x;
  const int bh = blockIdx.y, b = bh >> 4, h = bh & 15;
  const int t0 = iblk * 128;

  // Q fragments: A[row=t (lane&15)][k=d contiguous 8] -> direct 16B global loads
  bf16x8 aq[2][2];
#pragma unroll
  for (int mi = 0; mi < 2; ++mi)
#pragma unroll
    for (int kd = 0; kd < 2; ++kd)
      aq[mi][kd] = *reinterpret_cast<const bf16x8*>(
          &qkv[(size_t)(b * 4096 + t0 + w * 32 + mi * 16 + r16) * 3072 + h * 64 + kd * 32 + g4 * 8]);

  f32x4 o[2][4];
  float mrun[2][4], lrun[2][4];
#pragma unroll
  for (int mi = 0; mi < 2; ++mi) {
#pragma unroll
    for (int q = 0; q < 4; ++q) { mrun[mi][q] = -1e30f; lrun[mi][q] = 0.f; }
#pragma unroll
    for (int nd = 0; nd < 4; ++nd) o[mi][nd] = f32x4{0.f, 0.f, 0.f, 0.f};
  }

  const short* kpb = kp + (size_t)b * 1024 * 1024 + h * 64;          // [kk][d]
  const short* vtb = vpt + ((size_t)b * 1024 + h * 64) * 1024;       // [d][kk]

  const int ntiles = (iblk + 1 < 8) ? (iblk + 1) : 8;
  for (int jt = 0; jt < ntiles; ++jt) {
    const int kk0 = jt * 128;

    // S = Q @ Kp^T ; B-fragment: col=kk (r16), k=d contiguous -> direct global
    f32x4 s[2][8];
#pragma unroll
    for (int n = 0; n < 8; ++n) {
      const short* kr = &kpb[(size_t)(kk0 + n * 16 + r16) * 1024 + g4 * 8];
      bf16x8 bk0 = *reinterpret_cast<const bf16x8*>(kr);
      bf16x8 bk1 = *reinterpret_cast<const bf16x8*>(kr + 32);
      s[0][n] = __builtin_amdgcn_mfma_f32_16x16x32_bf16(aq[0][0], bk0, f32x4{0.f,0.f,0.f,0.f}, 0, 0, 0);
      s[0][n] = __builtin_amdgcn_mfma_f32_16x16x32_bf16(aq[0][1], bk1, s[0][n], 0, 0, 0);
      s[1][n] = __builtin_amdgcn_mfma_f32_16x16x32_bf16(aq[1][0], bk0, f32x4{0.f,0.f,0.f,0.f}, 0, 0, 0);
      s[1][n] = __builtin_amdgcn_mfma_f32_16x16x32_bf16(aq[1][1], bk1, s[1][n], 0, 0, 0);
    }

    if (jt == iblk) {  // diagonal tile: mask c > r
#pragma unroll
      for (int mi = 0; mi < 2; ++mi)
#pragma unroll
        for (int n = 0; n < 8; ++n)
#pragma unroll
          for (int q = 0; q < 4; ++q) {
            int r = w * 32 + mi * 16 + g4 * 4 + q;
            int c = n * 16 + r16;
            if (c > r) s[mi][n][q] = -1e30f;
          }
    }

    // online softmax update
#pragma unroll
    for (int mi = 0; mi < 2; ++mi)
#pragma unroll
      for (int q = 0; q < 4; ++q) {
        float rmax = s[mi][0][q];
#pragma unroll
        for (int n = 1; n < 8; ++n) rmax = fmaxf(rmax, s[mi][n][q]);
#pragma unroll
        for (int off = 1; off < 16; off <<= 1) rmax = fmaxf(rmax, __shfl_xor(rmax, off, 64));
        float mold = mrun[mi][q];
        float newm = fmaxf(mold, rmax);
        float corr = __expf(mold - newm);
        mrun[mi][q] = newm;
        float rsum = 0.f;
#pragma unroll
        for (int n = 0; n < 8; ++n) {
          float pv = __expf(s[mi][n][q] - newm);
          s[mi][n][q] = pv;
          rsum += pv;
        }
#pragma unroll
        for (int off = 1; off < 16; off <<= 1) rsum += __shfl_xor(rsum, off, 64);
        lrun[mi][q] = lrun[mi][q] * corr + rsum;
#pragma unroll
        for (int nd = 0; nd < 4; ++nd) o[mi][nd][q] = o[mi][nd][q] * corr;
      }

    // PV in two 64-col halves; P through wave-local LDS; V fragments direct from global
#pragma unroll
    for (int hf = 0; hf < 2; ++hf) {
#pragma unroll
      for (int mi = 0; mi < 2; ++mi)
#pragma unroll
        for (int q = 0; q < 4; ++q)
#pragma unroll
          for (int nn = 0; nn < 4; ++nn)
            P[w][mi * 16 + g4 * 4 + q][nn * 16 + r16] = f2bf(s[mi][hf * 4 + nn][q]);
#pragma unroll
      for (int kf = 0; kf < 2; ++kf) {
        bf16x8 ap0 = *reinterpret_cast<const bf16x8*>(&P[w][r16][kf * 32 + g4 * 8]);
        bf16x8 ap1 = *reinterpret_cast<const bf16x8*>(&P[w][16 + r16][kf * 32 + g4 * 8]);
#pragma unroll
        for (int nd = 0; nd < 4; ++nd) {
          bf16x8 bv = *reinterpret_cast<const bf16x8*>(
              &vtb[(size_t)(nd * 16 + r16) * 1024 + kk0 + hf * 64 + kf * 32 + g4 * 8]);
          o[0][nd] = __builtin_amdgcn_mfma_f32_16x16x32_bf16(ap0, bv, o[0][nd], 0, 0, 0);
          o[1][nd] = __builtin_amdgcn_mfma_f32_16x16x32_bf16(ap1, bv, o[1][nd], 0, 0, 0);
        }
      }
    }
  }

  // epilogue: y[b][t][h*64+dd] = O / l
#pragma unroll
  for (int mi = 0; mi < 2; ++mi)
#pragma unroll
    for (int q = 0; q < 4; ++q) {
      int tq = t0 + w * 32 + mi * 16 + g4 * 4 + q;
      float inv = 1.0f / lrun[mi][q];
#pragma unroll
      for (int nd = 0; nd < 4; ++nd)
        y[(size_t)(b * 4096 + tq) * 1024 + h * 64 + nd * 16 + r16] = f2bf(o[mi][nd][q] * inv);
    }
}

// ---------------- GEMM2: out = y @ W_proj + b (f32 out) ----------------
__global__ __launch_bounds__(256) void k_gemm_out(const short* __restrict__ A,
                                                  const short* __restrict__ BT,
                                                  const float* __restrict__ bias,
                                                  float* __restrict__ C) {
  __shared__ short As[128][40];
  __shared__ short Bs[128][40];
  const int tid = threadIdx.x, lane = tid & 63, w = tid >> 6;
  const int wm = w >> 1, wn = w & 1;
  const int r16 = lane & 15, g4 = lane >> 4;
  const int m0 = blockIdx.x * 128, n0 = blockIdx.y * 128;
  f32x4 acc[4][4];
#pragma unroll
  for (int i = 0; i < 4; ++i)
#pragma unroll
    for (int j = 0; j < 4; ++j) acc[i][j] = f32x4{0.f, 0.f, 0.f, 0.f};
  for (int k0 = 0; k0 < 1024; k0 += 32) {
#pragma unroll
    for (int it = 0; it < 2; ++it) {
      int slot = tid + it * 256;
      int row = slot >> 2, dg = slot & 3;
      *reinterpret_cast<bf16x8*>(&As[row][dg * 8]) =
          *reinterpret_cast<const bf16x8*>(&A[(size_t)(m0 + row) * 1024 + k0 + dg * 8]);
      *reinterpret_cast<bf16x8*>(&Bs[row][dg * 8]) =
          *reinterpret_cast<const bf16x8*>(&BT[(size_t)(n0 + row) * 1024 + k0 + dg * 8]);
    }
    __syncthreads();
    bf16x8 af[4], bfr[4];
#pragma unroll
    for (int i = 0; i < 4; ++i)
      af[i] = *reinterpret_cast<const bf16x8*>(&As[wm * 64 + i * 16 + r16][g4 * 8]);
#pragma unroll
    for (int j = 0; j < 4; ++j)
      bfr[j] = *reinterpret_cast<const bf16x8*>(&Bs[wn * 64 + j * 16 + r16][g4 * 8]);
#pragma unroll
    for (int i = 0; i < 4; ++i)
#pragma unroll
      for (int j = 0; j < 4; ++j)
        acc[i][j] = __builtin_amdgcn_mfma_f32_16x16x32_bf16(af[i], bfr[j], acc[i][j], 0, 0, 0);
    __syncthreads();
  }
#pragma unroll
  for (int i = 0; i < 4; ++i)
#pragma unroll
    for (int j = 0; j < 4; ++j) {
      int row = m0 + wm * 64 + i * 16 + g4 * 4;
      int col = n0 + wn * 64 + j * 16 + r16;
      float bv = bias[col];
#pragma unroll
      for (int q = 0; q < 4; ++q)
        C[(size_t)(row + q) * 1024 + col] = acc[i][j][q] + bv;
    }
}

extern "C" void kernel_launch(void* const* d_in, const int* in_sizes, int n_in,
                              void* d_out, int out_size, void* d_ws, size_t ws_size,
                              hipStream_t stream) {
  const float* x      = (const float*)d_in[0];
  const float* W_attn = (const float*)d_in[1];
  const float* b_attn = (const float*)d_in[2];
  const float* W_proj = (const float*)d_in[3];
  const float* b_proj = (const float*)d_in[4];
  const float* E      = (const float*)d_in[5];
  const float* F      = (const float*)d_in[6];
  float* out = (float*)d_out;

  char* ws = (char*)d_ws;
  short* xb  = (short*)(ws + 0);          //  32 MB: x bf16            (16384x1024)
  short* WaT = (short*)(ws + 33554432);   //   6 MB: W_attn^T bf16     (3072x1024)
  short* WpT = (short*)(ws + 39845888);   //   2 MB: W_proj^T bf16     (1024x1024)
  short* Et  = (short*)(ws + 41943040);   //   8 MB: E^T bf16          (1024x4096)
  short* Ft  = (short*)(ws + 50331648);   //   8 MB: F^T bf16          (1024x4096)
  short* qkv = (short*)(ws + 58720256);   //  96 MB: qkv bf16          (16384x3072)
  short* kp  = (short*)(ws + 159383552);  //   8 MB: k_proj bf16       (4x1024x1024)
  short* vpt = (short*)(ws + 167772160);  //   8 MB: v_proj^T bf16     (4x1024x1024)
  short* yb  = (short*)(ws + 176160768);  //  32 MB: attn out bf16     (16384x1024)

  k_convert<<<16384, 256, 0, stream>>>(x, xb, 16777216);
  k_transpose_cvt<<<dim3(96, 32), 256, 0, stream>>>(W_attn, WaT, 1024, 3072);
  k_transpose_cvt<<<dim3(32, 32), 256, 0, stream>>>(W_proj, WpT, 1024, 1024);
  k_transpose_cvt<<<dim3(32, 128), 256, 0, stream>>>(E, Et, 4096, 1024);
  k_transpose_cvt<<<dim3(32, 128), 256, 0, stream>>>(F, Ft, 4096, 1024);

  k_gemm_qkv<<<dim3(128, 24), 256, 0, stream>>>(xb, WaT, b_attn, qkv);
  k_proj<<<dim3(8, 8, 8), 256, 0, stream>>>(Et, Ft, qkv, kp, vpt);
  k_attn<<<dim3(32, 64), 256, 0, stream>>>(qkv, kp, vpt, yb);
  k_gemm_out<<<dim3(128, 8), 256, 0, stream>>>(yb, WpT, b_proj, out);
}

// Round 3
// 592.938 us; speedup vs baseline: 1.1187x; 1.1187x over previous
//
#include <hip/hip_runtime.h>
#include <stdint.h>

typedef short bf16x8 __attribute__((ext_vector_type(8)));
typedef short bf16x4 __attribute__((ext_vector_type(4)));
typedef float f32x4 __attribute__((ext_vector_type(4)));

__device__ __forceinline__ short f2bf(float f) {
  union { float f; uint32_t u; } v; v.f = f;
  uint32_t r = (v.u + 0x7FFFu + ((v.u >> 16) & 1u)) >> 16;
  return (short)(uint16_t)r;
}

// ---------------- elementwise f32 -> bf16 ----------------
__global__ __launch_bounds__(256) void k_convert(const float* __restrict__ in,
                                                 short* __restrict__ out, int n) {
  int i = (blockIdx.x * 256 + threadIdx.x) * 4;
  if (i >= n) return;
  float4 v = *reinterpret_cast<const float4*>(in + i);
  bf16x4 o; o[0] = f2bf(v.x); o[1] = f2bf(v.y); o[2] = f2bf(v.z); o[3] = f2bf(v.w);
  *reinterpret_cast<bf16x4*>(out + i) = o;
}

// ---------------- transpose + convert: out[C][R] = bf16(in[R][C]) ----------------
__global__ __launch_bounds__(256) void k_transpose_cvt(const float* __restrict__ in,
                                                       short* __restrict__ out,
                                                       int R, int C) {
  __shared__ float tile[32][33];
  int r0 = blockIdx.y * 32, c0 = blockIdx.x * 32;
  int tx = threadIdx.x & 31, ty = threadIdx.x >> 5;
#pragma unroll
  for (int j = 0; j < 4; ++j)
    tile[ty + j * 8][tx] = in[(size_t)(r0 + ty + j * 8) * C + c0 + tx];
  __syncthreads();
#pragma unroll
  for (int j = 0; j < 4; ++j)
    out[(size_t)(c0 + ty + j * 8) * R + r0 + tx] = f2bf(tile[tx][ty + j * 8]);
}

// ---------------- GEMM1: qkv = x @ W_attn + b ----------------
__global__ __launch_bounds__(256) void k_gemm_qkv(const short* __restrict__ A,
                                                  const short* __restrict__ BT,
                                                  const float* __restrict__ bias,
                                                  short* __restrict__ C) {
  __shared__ short As[128][40];
  __shared__ short Bs[128][40];
  const int tid = threadIdx.x, lane = tid & 63, w = tid >> 6;
  const int wm = w >> 1, wn = w & 1;
  const int r16 = lane & 15, g4 = lane >> 4;
  const int m0 = blockIdx.x * 128, n0 = blockIdx.y * 128;
  f32x4 acc[4][4];
#pragma unroll
  for (int i = 0; i < 4; ++i)
#pragma unroll
    for (int j = 0; j < 4; ++j) acc[i][j] = f32x4{0.f, 0.f, 0.f, 0.f};
  for (int k0 = 0; k0 < 1024; k0 += 32) {
#pragma unroll
    for (int it = 0; it < 2; ++it) {
      int slot = tid + it * 256;
      int row = slot >> 2, dg = slot & 3;
      *reinterpret_cast<bf16x8*>(&As[row][dg * 8]) =
          *reinterpret_cast<const bf16x8*>(&A[(size_t)(m0 + row) * 1024 + k0 + dg * 8]);
      *reinterpret_cast<bf16x8*>(&Bs[row][dg * 8]) =
          *reinterpret_cast<const bf16x8*>(&BT[(size_t)(n0 + row) * 1024 + k0 + dg * 8]);
    }
    __syncthreads();
    bf16x8 af[4], bfr[4];
#pragma unroll
    for (int i = 0; i < 4; ++i)
      af[i] = *reinterpret_cast<const bf16x8*>(&As[wm * 64 + i * 16 + r16][g4 * 8]);
#pragma unroll
    for (int j = 0; j < 4; ++j)
      bfr[j] = *reinterpret_cast<const bf16x8*>(&Bs[wn * 64 + j * 16 + r16][g4 * 8]);
#pragma unroll
    for (int i = 0; i < 4; ++i)
#pragma unroll
      for (int j = 0; j < 4; ++j)
        acc[i][j] = __builtin_amdgcn_mfma_f32_16x16x32_bf16(af[i], bfr[j], acc[i][j], 0, 0, 0);
    __syncthreads();
  }
#pragma unroll
  for (int i = 0; i < 4; ++i)
#pragma unroll
    for (int j = 0; j < 4; ++j) {
      int row = m0 + wm * 64 + i * 16 + g4 * 4;
      int col = n0 + wn * 64 + j * 16 + r16;
      float bv = bias[col];
#pragma unroll
      for (int q = 0; q < 4; ++q)
        C[(size_t)(row + q) * 3072 + col] = f2bf(acc[i][j][q] + bv);
    }
}

// ---------------- Projection ----------------
// K: kp[b][kk][c] = sum_t Et[kk][t]*k[b][t][c] * 1/8   (row-major)
// V: vpt[b][c][kk] = sum_t Ft[kk][t]*v[b][t][c]        (TRANSPOSED for attn PV)
__global__ __launch_bounds__(256) void k_proj(const short* __restrict__ Et,
                                              const short* __restrict__ Ft,
                                              const short* __restrict__ qkv,
                                              short* __restrict__ kp,
                                              short* __restrict__ vpt) {
  const int z = blockIdx.z, b = z >> 1, which = z & 1;
  const short* __restrict__ AT = which ? Ft : Et;
  const int koff = which ? 2048 : 1024;
  __shared__ short As[128][40];
  __shared__ short Bs[128][40];
  const int tid = threadIdx.x, lane = tid & 63, w = tid >> 6;
  const int wm = w >> 1, wn = w & 1;
  const int r16 = lane & 15, g4 = lane >> 4;
  const int m0 = blockIdx.x * 128, n0 = blockIdx.y * 128;
  const int cLane = tid & 127, tHalf = tid >> 7;
  f32x4 acc[4][4];
#pragma unroll
  for (int i = 0; i < 4; ++i)
#pragma unroll
    for (int j = 0; j < 4; ++j) acc[i][j] = f32x4{0.f, 0.f, 0.f, 0.f};
  for (int t0 = 0; t0 < 4096; t0 += 32) {
#pragma unroll
    for (int it = 0; it < 2; ++it) {
      int slot = tid + it * 256;
      int row = slot >> 2, dg = slot & 3;
      *reinterpret_cast<bf16x8*>(&As[row][dg * 8]) =
          *reinterpret_cast<const bf16x8*>(&AT[(size_t)(m0 + row) * 4096 + t0 + dg * 8]);
    }
#pragma unroll
    for (int it = 0; it < 16; ++it) {
      int t = tHalf * 16 + it;
      Bs[cLane][t] = qkv[(size_t)(b * 4096 + t0 + t) * 3072 + koff + n0 + cLane];
    }
    __syncthreads();
    bf16x8 af[4], bfr[4];
#pragma unroll
    for (int i = 0; i < 4; ++i)
      af[i] = *reinterpret_cast<const bf16x8*>(&As[wm * 64 + i * 16 + r16][g4 * 8]);
#pragma unroll
    for (int j = 0; j < 4; ++j)
      bfr[j] = *reinterpret_cast<const bf16x8*>(&Bs[wn * 64 + j * 16 + r16][g4 * 8]);
#pragma unroll
    for (int i = 0; i < 4; ++i)
#pragma unroll
      for (int j = 0; j < 4; ++j)
        acc[i][j] = __builtin_amdgcn_mfma_f32_16x16x32_bf16(af[i], bfr[j], acc[i][j], 0, 0, 0);
    __syncthreads();
  }
  if (which) {
    // transposed store: vpt[b][col][row..row+3]
#pragma unroll
    for (int i = 0; i < 4; ++i)
#pragma unroll
      for (int j = 0; j < 4; ++j) {
        int row = m0 + wm * 64 + i * 16 + g4 * 4;
        int col = n0 + wn * 64 + j * 16 + r16;
        bf16x4 ov;
#pragma unroll
        for (int q = 0; q < 4; ++q) ov[q] = f2bf(acc[i][j][q]);
        *reinterpret_cast<bf16x4*>(&vpt[((size_t)(b * 1024) + col) * 1024 + row]) = ov;
      }
  } else {
#pragma unroll
    for (int i = 0; i < 4; ++i)
#pragma unroll
      for (int j = 0; j < 4; ++j) {
        int row = m0 + wm * 64 + i * 16 + g4 * 4;
        int col = n0 + wn * 64 + j * 16 + r16;
#pragma unroll
        for (int q = 0; q < 4; ++q)
          kp[((size_t)(b * 1024) + row + q) * 1024 + col] = f2bf(acc[i][j][q] * 0.125f);
      }
  }
}

// ---------------- Flash attention: LDS-staged K/V with T2 XOR swizzle ----------------
// Ks: [kk 0..127][d 0..63], row = 128B, byte(kk,dbyte) = kk*128 + (dbyte ^ ((kk&7)<<4))
// Vt: [d 0..63][kk 0..127], row = 256B, byte(d,kbyte)  = d*256  + (kbyte ^ ((d&7)<<4))
__global__ __launch_bounds__(256, 3) void k_attn(const short* __restrict__ qkv,
                                                 const short* __restrict__ kp,
                                                 const short* __restrict__ vpt,
                                                 short* __restrict__ y) {
  __shared__ char KsB[128 * 128];        // 16 KB
  __shared__ char VtB[64 * 256];         // 16 KB
  __shared__ short P[4][32][72];         // 18 KB per-wave P buffer
  const int tid = threadIdx.x, lane = tid & 63, w = tid >> 6;
  const int r16 = lane & 15, g4 = lane >> 4;
  const int iblk = blockIdx.x;
  const int bh = blockIdx.y, b = bh >> 4, h = bh & 15;
  const int t0 = iblk * 128;

  // Q fragments: once per block, direct global (small)
  bf16x8 aq[2][2];
#pragma unroll
  for (int mi = 0; mi < 2; ++mi)
#pragma unroll
    for (int kd = 0; kd < 2; ++kd)
      aq[mi][kd] = *reinterpret_cast<const bf16x8*>(
          &qkv[(size_t)(b * 4096 + t0 + w * 32 + mi * 16 + r16) * 3072 + h * 64 + kd * 32 + g4 * 8]);

  f32x4 o[2][4];
  float mrun[2][4], lrun[2][4];
#pragma unroll
  for (int mi = 0; mi < 2; ++mi) {
#pragma unroll
    for (int q = 0; q < 4; ++q) { mrun[mi][q] = -1e30f; lrun[mi][q] = 0.f; }
#pragma unroll
    for (int nd = 0; nd < 4; ++nd) o[mi][nd] = f32x4{0.f, 0.f, 0.f, 0.f};
  }

  const short* kpb = kp + (size_t)b * 1024 * 1024 + h * 64;      // [kk][d]
  const short* vtb = vpt + ((size_t)b * 1024 + h * 64) * 1024;   // [d][kk]

  // precomputed swizzle constants for this thread's fragment reads
  const int swz = (r16 & 7) << 4;

  const int ntiles = (iblk + 1 < 8) ? (iblk + 1) : 8;
  for (int jt = 0; jt < ntiles; ++jt) {
    const int kk0 = jt * 128;
    __syncthreads();
    // stage K tile: 128 rows x 8 groups of 16B
#pragma unroll
    for (int it = 0; it < 4; ++it) {
      int slot = tid + it * 256;
      int kk = slot >> 3, c8 = slot & 7;
      bf16x8 kv = *reinterpret_cast<const bf16x8*>(&kpb[(size_t)(kk0 + kk) * 1024 + c8 * 8]);
      *reinterpret_cast<bf16x8*>(&KsB[kk * 128 + ((c8 * 16) ^ ((kk & 7) << 4))]) = kv;
      // stage V tile: 64 rows x 16 groups of 16B
      int d = slot >> 4, c16 = slot & 15;
      bf16x8 vv = *reinterpret_cast<const bf16x8*>(&vtb[(size_t)d * 1024 + kk0 + c16 * 8]);
      *reinterpret_cast<bf16x8*>(&VtB[d * 256 + ((c16 * 16) ^ ((d & 7) << 4))]) = vv;
    }
    __syncthreads();

    // S = Q @ Kp^T  (B-frag col = kk0+n*16+r16, k = d)
    f32x4 s[2][8];
#pragma unroll
    for (int n = 0; n < 8; ++n) {
      const char* kr = &KsB[(n * 16 + r16) * 128];
      bf16x8 bk0 = *reinterpret_cast<const bf16x8*>(kr + ((g4 * 16) ^ swz));
      bf16x8 bk1 = *reinterpret_cast<const bf16x8*>(kr + ((64 + g4 * 16) ^ swz));
      s[0][n] = __builtin_amdgcn_mfma_f32_16x16x32_bf16(aq[0][0], bk0, f32x4{0.f,0.f,0.f,0.f}, 0, 0, 0);
      s[0][n] = __builtin_amdgcn_mfma_f32_16x16x32_bf16(aq[0][1], bk1, s[0][n], 0, 0, 0);
      s[1][n] = __builtin_amdgcn_mfma_f32_16x16x32_bf16(aq[1][0], bk0, f32x4{0.f,0.f,0.f,0.f}, 0, 0, 0);
      s[1][n] = __builtin_amdgcn_mfma_f32_16x16x32_bf16(aq[1][1], bk1, s[1][n], 0, 0, 0);
    }

    if (jt == iblk) {  // diagonal tile: mask c > r
#pragma unroll
      for (int mi = 0; mi < 2; ++mi)
#pragma unroll
        for (int n = 0; n < 8; ++n)
#pragma unroll
          for (int q = 0; q < 4; ++q) {
            int r = w * 32 + mi * 16 + g4 * 4 + q;
            int c = n * 16 + r16;
            if (c > r) s[mi][n][q] = -1e30f;
          }
    }

    // online softmax update
#pragma unroll
    for (int mi = 0; mi < 2; ++mi)
#pragma unroll
      for (int q = 0; q < 4; ++q) {
        float rmax = s[mi][0][q];
#pragma unroll
        for (int n = 1; n < 8; ++n) rmax = fmaxf(rmax, s[mi][n][q]);
#pragma unroll
        for (int off = 1; off < 16; off <<= 1) rmax = fmaxf(rmax, __shfl_xor(rmax, off, 64));
        float mold = mrun[mi][q];
        float newm = fmaxf(mold, rmax);
        float corr = __expf(mold - newm);
        mrun[mi][q] = newm;
        float rsum = 0.f;
#pragma unroll
        for (int n = 0; n < 8; ++n) {
          float pv = __expf(s[mi][n][q] - newm);
          s[mi][n][q] = pv;
          rsum += pv;
        }
#pragma unroll
        for (int off = 1; off < 16; off <<= 1) rsum += __shfl_xor(rsum, off, 64);
        lrun[mi][q] = lrun[mi][q] * corr + rsum;
#pragma unroll
        for (int nd = 0; nd < 4; ++nd) o[mi][nd][q] = o[mi][nd][q] * corr;
      }

    // PV in two 64-col halves; P through wave-local LDS; V B-frags from swizzled LDS
#pragma unroll
    for (int hf = 0; hf < 2; ++hf) {
#pragma unroll
      for (int mi = 0; mi < 2; ++mi)
#pragma unroll
        for (int q = 0; q < 4; ++q)
#pragma unroll
          for (int nn = 0; nn < 4; ++nn)
            P[w][mi * 16 + g4 * 4 + q][nn * 16 + r16] = f2bf(s[mi][hf * 4 + nn][q]);
#pragma unroll
      for (int kf = 0; kf < 2; ++kf) {
        bf16x8 ap0 = *reinterpret_cast<const bf16x8*>(&P[w][r16][kf * 32 + g4 * 8]);
        bf16x8 ap1 = *reinterpret_cast<const bf16x8*>(&P[w][16 + r16][kf * 32 + g4 * 8]);
#pragma unroll
        for (int nd = 0; nd < 4; ++nd) {
          const char* vr = &VtB[(nd * 16 + r16) * 256];
          bf16x8 bv = *reinterpret_cast<const bf16x8*>(
              vr + ((hf * 128 + kf * 64 + g4 * 16) ^ swz));
          o[0][nd] = __builtin_amdgcn_mfma_f32_16x16x32_bf16(ap0, bv, o[0][nd], 0, 0, 0);
          o[1][nd] = __builtin_amdgcn_mfma_f32_16x16x32_bf16(ap1, bv, o[1][nd], 0, 0, 0);
        }
      }
    }
  }

  // epilogue: y[b][t][h*64+dd] = O / l
#pragma unroll
  for (int mi = 0; mi < 2; ++mi)
#pragma unroll
    for (int q = 0; q < 4; ++q) {
      int tq = t0 + w * 32 + mi * 16 + g4 * 4 + q;
      float inv = 1.0f / lrun[mi][q];
#pragma unroll
      for (int nd = 0; nd < 4; ++nd)
        y[(size_t)(b * 4096 + tq) * 1024 + h * 64 + nd * 16 + r16] = f2bf(o[mi][nd][q] * inv);
    }
}

// ---------------- GEMM2: out = y @ W_proj + b (f32 out) ----------------
__global__ __launch_bounds__(256) void k_gemm_out(const short* __restrict__ A,
                                                  const short* __restrict__ BT,
                                                  const float* __restrict__ bias,
                                                  float* __restrict__ C) {
  __shared__ short As[128][40];
  __shared__ short Bs[128][40];
  const int tid = threadIdx.x, lane = tid & 63, w = tid >> 6;
  const int wm = w >> 1, wn = w & 1;
  const int r16 = lane & 15, g4 = lane >> 4;
  const int m0 = blockIdx.x * 128, n0 = blockIdx.y * 128;
  f32x4 acc[4][4];
#pragma unroll
  for (int i = 0; i < 4; ++i)
#pragma unroll
    for (int j = 0; j < 4; ++j) acc[i][j] = f32x4{0.f, 0.f, 0.f, 0.f};
  for (int k0 = 0; k0 < 1024; k0 += 32) {
#pragma unroll
    for (int it = 0; it < 2; ++it) {
      int slot = tid + it * 256;
      int row = slot >> 2, dg = slot & 3;
      *reinterpret_cast<bf16x8*>(&As[row][dg * 8]) =
          *reinterpret_cast<const bf16x8*>(&A[(size_t)(m0 + row) * 1024 + k0 + dg * 8]);
      *reinterpret_cast<bf16x8*>(&Bs[row][dg * 8]) =
          *reinterpret_cast<const bf16x8*>(&BT[(size_t)(n0 + row) * 1024 + k0 + dg * 8]);
    }
    __syncthreads();
    bf16x8 af[4], bfr[4];
#pragma unroll
    for (int i = 0; i < 4; ++i)
      af[i] = *reinterpret_cast<const bf16x8*>(&As[wm * 64 + i * 16 + r16][g4 * 8]);
#pragma unroll
    for (int j = 0; j < 4; ++j)
      bfr[j] = *reinterpret_cast<const bf16x8*>(&Bs[wn * 64 + j * 16 + r16][g4 * 8]);
#pragma unroll
    for (int i = 0; i < 4; ++i)
#pragma unroll
      for (int j = 0; j < 4; ++j)
        acc[i][j] = __builtin_amdgcn_mfma_f32_16x16x32_bf16(af[i], bfr[j], acc[i][j], 0, 0, 0);
    __syncthreads();
  }
#pragma unroll
  for (int i = 0; i < 4; ++i)
#pragma unroll
    for (int j = 0; j < 4; ++j) {
      int row = m0 + wm * 64 + i * 16 + g4 * 4;
      int col = n0 + wn * 64 + j * 16 + r16;
      float bv = bias[col];
#pragma unroll
      for (int q = 0; q < 4; ++q)
        C[(size_t)(row + q) * 1024 + col] = acc[i][j][q] + bv;
    }
}

extern "C" void kernel_launch(void* const* d_in, const int* in_sizes, int n_in,
                              void* d_out, int out_size, void* d_ws, size_t ws_size,
                              hipStream_t stream) {
  const float* x      = (const float*)d_in[0];
  const float* W_attn = (const float*)d_in[1];
  const float* b_attn = (const float*)d_in[2];
  const float* W_proj = (const float*)d_in[3];
  const float* b_proj = (const float*)d_in[4];
  const float* E      = (const float*)d_in[5];
  const float* F      = (const float*)d_in[6];
  float* out = (float*)d_out;

  char* ws = (char*)d_ws;
  short* xb  = (short*)(ws + 0);          //  32 MB: x bf16            (16384x1024)
  short* WaT = (short*)(ws + 33554432);   //   6 MB: W_attn^T bf16     (3072x1024)
  short* WpT = (short*)(ws + 39845888);   //   2 MB: W_proj^T bf16     (1024x1024)
  short* Et  = (short*)(ws + 41943040);   //   8 MB: E^T bf16          (1024x4096)
  short* Ft  = (short*)(ws + 50331648);   //   8 MB: F^T bf16          (1024x4096)
  short* qkv = (short*)(ws + 58720256);   //  96 MB: qkv bf16          (16384x3072)
  short* kp  = (short*)(ws + 159383552);  //   8 MB: k_proj bf16       (4x1024x1024)
  short* vpt = (short*)(ws + 167772160);  //   8 MB: v_proj^T bf16     (4x1024x1024)
  short* yb  = (short*)(ws + 176160768);  //  32 MB: attn out bf16     (16384x1024)

  k_convert<<<16384, 256, 0, stream>>>(x, xb, 16777216);
  k_transpose_cvt<<<dim3(96, 32), 256, 0, stream>>>(W_attn, WaT, 1024, 3072);
  k_transpose_cvt<<<dim3(32, 32), 256, 0, stream>>>(W_proj, WpT, 1024, 1024);
  k_transpose_cvt<<<dim3(32, 128), 256, 0, stream>>>(E, Et, 4096, 1024);
  k_transpose_cvt<<<dim3(32, 128), 256, 0, stream>>>(F, Ft, 4096, 1024);

  k_gemm_qkv<<<dim3(128, 24), 256, 0, stream>>>(xb, WaT, b_attn, qkv);
  k_proj<<<dim3(8, 8, 8), 256, 0, stream>>>(Et, Ft, qkv, kp, vpt);
  k_attn<<<dim3(32, 64), 256, 0, stream>>>(qkv, kp, vpt, yb);
  k_gemm_out<<<dim3(128, 8), 256, 0, stream>>>(yb, WpT, b_proj, out);
}

// Round 4
// 496.440 us; speedup vs baseline: 1.3361x; 1.1944x over previous
//
#include <hip/hip_runtime.h>
#include <stdint.h>

typedef short bf16x8 __attribute__((ext_vector_type(8)));
typedef short bf16x4 __attribute__((ext_vector_type(4)));
typedef float f32x4 __attribute__((ext_vector_type(4)));
typedef float f32x16 __attribute__((ext_vector_type(16)));
typedef int i32x4 __attribute__((ext_vector_type(4)));

__device__ __forceinline__ short f2bf(float f) {
  union { float f; uint32_t u; } v; v.f = f;
  uint32_t r = (v.u + 0x7FFFu + ((v.u >> 16) & 1u)) >> 16;
  return (short)(uint16_t)r;
}

__device__ __forceinline__ int cvtpk(float lo, float hi) {
  int r;
  asm("v_cvt_pk_bf16_f32 %0, %1, %2" : "=v"(r) : "v"(lo), "v"(hi));
  return r;
}

// ---------------- elementwise f32 -> bf16 ----------------
__global__ __launch_bounds__(256) void k_convert(const float* __restrict__ in,
                                                 short* __restrict__ out, int n) {
  int i = (blockIdx.x * 256 + threadIdx.x) * 4;
  if (i >= n) return;
  float4 v = *reinterpret_cast<const float4*>(in + i);
  bf16x4 o; o[0] = f2bf(v.x); o[1] = f2bf(v.y); o[2] = f2bf(v.z); o[3] = f2bf(v.w);
  *reinterpret_cast<bf16x4*>(out + i) = o;
}

// ---------------- transpose + convert: out[C][R] = bf16(in[R][C]) ----------------
__global__ __launch_bounds__(256) void k_transpose_cvt(const float* __restrict__ in,
                                                       short* __restrict__ out,
                                                       int R, int C) {
  __shared__ float tile[32][33];
  int r0 = blockIdx.y * 32, c0 = blockIdx.x * 32;
  int tx = threadIdx.x & 31, ty = threadIdx.x >> 5;
#pragma unroll
  for (int j = 0; j < 4; ++j)
    tile[ty + j * 8][tx] = in[(size_t)(r0 + ty + j * 8) * C + c0 + tx];
  __syncthreads();
#pragma unroll
  for (int j = 0; j < 4; ++j)
    out[(size_t)(c0 + ty + j * 8) * R + r0 + tx] = f2bf(tile[tx][ty + j * 8]);
}

// ---------------- GEMM1: qkv = x @ W_attn + b ----------------
// q part -> qb[16384][1024] row-major; k,v parts -> kT/vT[b][c][t] (transposed)
__global__ __launch_bounds__(256) void k_gemm_qkv(const short* __restrict__ A,
                                                  const short* __restrict__ BT,
                                                  const float* __restrict__ bias,
                                                  short* __restrict__ qb,
                                                  short* __restrict__ kT,
                                                  short* __restrict__ vT) {
  __shared__ short As[128][40];
  __shared__ short Bs[128][40];
  const int tid = threadIdx.x, lane = tid & 63, w = tid >> 6;
  const int wm = w >> 1, wn = w & 1;
  const int r16 = lane & 15, g4 = lane >> 4;
  const int m0 = blockIdx.x * 128, n0 = blockIdx.y * 128;
  f32x4 acc[4][4];
#pragma unroll
  for (int i = 0; i < 4; ++i)
#pragma unroll
    for (int j = 0; j < 4; ++j) acc[i][j] = f32x4{0.f, 0.f, 0.f, 0.f};
  for (int k0 = 0; k0 < 1024; k0 += 32) {
#pragma unroll
    for (int it = 0; it < 2; ++it) {
      int slot = tid + it * 256;
      int row = slot >> 2, dg = slot & 3;
      *reinterpret_cast<bf16x8*>(&As[row][dg * 8]) =
          *reinterpret_cast<const bf16x8*>(&A[(size_t)(m0 + row) * 1024 + k0 + dg * 8]);
      *reinterpret_cast<bf16x8*>(&Bs[row][dg * 8]) =
          *reinterpret_cast<const bf16x8*>(&BT[(size_t)(n0 + row) * 1024 + k0 + dg * 8]);
    }
    __syncthreads();
    bf16x8 af[4], bfr[4];
#pragma unroll
    for (int i = 0; i < 4; ++i)
      af[i] = *reinterpret_cast<const bf16x8*>(&As[wm * 64 + i * 16 + r16][g4 * 8]);
#pragma unroll
    for (int j = 0; j < 4; ++j)
      bfr[j] = *reinterpret_cast<const bf16x8*>(&Bs[wn * 64 + j * 16 + r16][g4 * 8]);
#pragma unroll
    for (int i = 0; i < 4; ++i)
#pragma unroll
      for (int j = 0; j < 4; ++j)
        acc[i][j] = __builtin_amdgcn_mfma_f32_16x16x32_bf16(af[i], bfr[j], acc[i][j], 0, 0, 0);
    __syncthreads();
  }
  const int seg = n0 >> 10;  // 0=q, 1=k, 2=v (blocks never straddle segments)
#pragma unroll
  for (int i = 0; i < 4; ++i)
#pragma unroll
    for (int j = 0; j < 4; ++j) {
      int row = m0 + wm * 64 + i * 16 + g4 * 4;
      int colg = n0 + wn * 64 + j * 16 + r16;
      float bv = bias[colg];
      if (seg == 0) {
#pragma unroll
        for (int q = 0; q < 4; ++q)
          qb[(size_t)(row + q) * 1024 + colg] = f2bf(acc[i][j][q] + bv);
      } else {
        int c = colg & 1023;
        int bb = row >> 12, t = row & 4095;
        short* dst = (seg == 1) ? kT : vT;
        bf16x4 ov;
#pragma unroll
        for (int q = 0; q < 4; ++q) ov[q] = f2bf(acc[i][j][q] + bv);
        *reinterpret_cast<bf16x4*>(&dst[((size_t)(bb << 10) + c) * 4096 + t]) = ov;
      }
    }
}

// ---------------- Projection (both operands K(t)-contiguous now) ----------------
// which=0: kp[b][kk][c] = (sum_t Et[kk][t]*kT[b][c][t]) / 8
// which=1: vpt[b][c][kk] = sum_t Ft[kk][t]*vT[b][c][t]   (transposed store)
__global__ __launch_bounds__(256) void k_proj(const short* __restrict__ Et,
                                              const short* __restrict__ Ft,
                                              const short* __restrict__ kT,
                                              const short* __restrict__ vT,
                                              short* __restrict__ kp,
                                              short* __restrict__ vpt) {
  const int z = blockIdx.z, b = z >> 1, which = z & 1;
  const short* __restrict__ AT = which ? Ft : Et;
  const short* __restrict__ BT = (which ? vT : kT) + ((size_t)b << 10) * 4096;
  __shared__ short As[128][40];
  __shared__ short Bs[128][40];
  const int tid = threadIdx.x, lane = tid & 63, w = tid >> 6;
  const int wm = w >> 1, wn = w & 1;
  const int r16 = lane & 15, g4 = lane >> 4;
  const int m0 = blockIdx.x * 128, n0 = blockIdx.y * 128;
  f32x4 acc[4][4];
#pragma unroll
  for (int i = 0; i < 4; ++i)
#pragma unroll
    for (int j = 0; j < 4; ++j) acc[i][j] = f32x4{0.f, 0.f, 0.f, 0.f};
  for (int t0 = 0; t0 < 4096; t0 += 32) {
#pragma unroll
    for (int it = 0; it < 2; ++it) {
      int slot = tid + it * 256;
      int row = slot >> 2, dg = slot & 3;
      *reinterpret_cast<bf16x8*>(&As[row][dg * 8]) =
          *reinterpret_cast<const bf16x8*>(&AT[(size_t)(m0 + row) * 4096 + t0 + dg * 8]);
      *reinterpret_cast<bf16x8*>(&Bs[row][dg * 8]) =
          *reinterpret_cast<const bf16x8*>(&BT[(size_t)(n0 + row) * 4096 + t0 + dg * 8]);
    }
    __syncthreads();
    bf16x8 af[4], bfr[4];
#pragma unroll
    for (int i = 0; i < 4; ++i)
      af[i] = *reinterpret_cast<const bf16x8*>(&As[wm * 64 + i * 16 + r16][g4 * 8]);
#pragma unroll
    for (int j = 0; j < 4; ++j)
      bfr[j] = *reinterpret_cast<const bf16x8*>(&Bs[wn * 64 + j * 16 + r16][g4 * 8]);
#pragma unroll
    for (int i = 0; i < 4; ++i)
#pragma unroll
      for (int j = 0; j < 4; ++j)
        acc[i][j] = __builtin_amdgcn_mfma_f32_16x16x32_bf16(af[i], bfr[j], acc[i][j], 0, 0, 0);
    __syncthreads();
  }
  if (which) {
#pragma unroll
    for (int i = 0; i < 4; ++i)
#pragma unroll
      for (int j = 0; j < 4; ++j) {
        int row = m0 + wm * 64 + i * 16 + g4 * 4;   // kk
        int col = n0 + wn * 64 + j * 16 + r16;      // c
        bf16x4 ov;
#pragma unroll
        for (int q = 0; q < 4; ++q) ov[q] = f2bf(acc[i][j][q]);
        *reinterpret_cast<bf16x4*>(&vpt[((size_t)(b * 1024) + col) * 1024 + row]) = ov;
      }
  } else {
#pragma unroll
    for (int i = 0; i < 4; ++i)
#pragma unroll
      for (int j = 0; j < 4; ++j) {
        int row = m0 + wm * 64 + i * 16 + g4 * 4;
        int col = n0 + wn * 64 + j * 16 + r16;
#pragma unroll
        for (int q = 0; q < 4; ++q)
          kp[((size_t)(b * 1024) + row + q) * 1024 + col] = f2bf(acc[i][j][q] * 0.125f);
      }
  }
}

// ---------------- Flash attention: swapped 32x32x16 MFMA, in-register P ----------------
// S^T[kk][t] = mfma(A=Kp, B=Q^T); O^T[d][t] = mfma(A=V^T, B=P^T)
// Lane (hi=lane>>5, r32=lane&31) owns q-row T = t0 + w*32 + r32 entirely.
__global__ __launch_bounds__(256, 3) void k_attn(const short* __restrict__ qb,
                                                 const short* __restrict__ kp,
                                                 const short* __restrict__ vpt,
                                                 short* __restrict__ y) {
  __shared__ __align__(16) char KsB[128 * 128];   // [kk][d] swizzled, 16 KB
  __shared__ __align__(16) char VtB[64 * 256];    // [d][kk] swizzled, 16 KB
  const int tid = threadIdx.x, lane = tid & 63, w = tid >> 6;
  const int r32 = lane & 31, hi = lane >> 5;
  const int iblk = blockIdx.x;
  const int bh = blockIdx.y, b = bh >> 4, h = bh & 15;
  const int t0 = iblk * 128;
  const int tl = w * 32 + r32;          // local row
  const int T = t0 + tl;                // global row (within b)

  // Q B-fragments: B[k=d][col=t]; lane holds Q[T][d = kd*16 + hi*8 + i]
  bf16x8 qf[4];
#pragma unroll
  for (int kd = 0; kd < 4; ++kd)
    qf[kd] = *reinterpret_cast<const bf16x8*>(
        &qb[(size_t)(b * 4096 + T) * 1024 + h * 64 + kd * 16 + hi * 8]);

  f32x16 o[2];
#pragma unroll
  for (int i = 0; i < 16; ++i) { o[0][i] = 0.f; o[1][i] = 0.f; }
  float mrun = -1e30f, lrun = 0.f;

  const short* kpb = kp + ((size_t)b << 20) + h * 64;             // [kk][c]
  const short* vtb = vpt + (((size_t)b << 10) + h * 64) * 1024;   // [c][kk]

  const int ntiles = (iblk + 1 < 8) ? (iblk + 1) : 8;
  for (int jt = 0; jt < ntiles; ++jt) {
    const int kk0 = jt * 128;
    __syncthreads();
#pragma unroll
    for (int it = 0; it < 4; ++it) {
      int slot = tid + it * 256;
      int kk = slot >> 3, c8 = slot & 7;
      bf16x8 kv = *reinterpret_cast<const bf16x8*>(&kpb[(size_t)(kk0 + kk) * 1024 + c8 * 8]);
      *reinterpret_cast<bf16x8*>(&KsB[kk * 128 + ((c8 * 16) ^ ((kk & 7) << 4))]) = kv;
      int d = slot >> 4, c16 = slot & 15;
      bf16x8 vv = *reinterpret_cast<const bf16x8*>(&vtb[(size_t)d * 1024 + kk0 + c16 * 8]);
      *reinterpret_cast<bf16x8*>(&VtB[d * 256 + ((c16 * 16) ^ ((d & 7) << 4))]) = vv;
    }
    __syncthreads();

#pragma unroll
    for (int st = 0; st < 2; ++st) {          // 64-kk sub-tiles
      // --- QK^T (swapped): s[ni] = S^T[kk = (2st+ni)*32 .. +31][t=r32]
      f32x16 s[2];
#pragma unroll
      for (int i = 0; i < 16; ++i) { s[0][i] = 0.f; s[1][i] = 0.f; }
#pragma unroll
      for (int ni = 0; ni < 2; ++ni) {
        int n = st * 2 + ni;
#pragma unroll
        for (int kd = 0; kd < 4; ++kd) {
          int row = n * 32 + r32;
          bf16x8 kf = *reinterpret_cast<const bf16x8*>(
              &KsB[row * 128 + ((kd * 32 + hi * 16) ^ ((row & 7) << 4))]);
          s[ni] = __builtin_amdgcn_mfma_f32_32x32x16_bf16(kf, qf[kd], s[ni], 0, 0, 0);
        }
      }

      if (jt == iblk) {  // causal mask on diagonal tile: kk_local > t_local
#pragma unroll
        for (int ni = 0; ni < 2; ++ni)
#pragma unroll
          for (int j = 0; j < 16; ++j) {
            int kkl = (st * 2 + ni) * 32 + (j & 3) + 8 * (j >> 2) + 4 * hi;
            if (kkl > tl) s[ni][j] = -1e30f;
          }
      }

      // --- online softmax (row = lane's own T; partner = lane^32)
      float pmax = s[0][0];
#pragma unroll
      for (int j = 1; j < 16; ++j) pmax = fmaxf(pmax, s[0][j]);
#pragma unroll
      for (int j = 0; j < 16; ++j) pmax = fmaxf(pmax, s[1][j]);
      pmax = fmaxf(pmax, __shfl_xor(pmax, 32, 64));
      float newm = fmaxf(mrun, pmax);
      float corr = __expf(mrun - newm);
      mrun = newm;
      float rsum = 0.f;
#pragma unroll
      for (int ni = 0; ni < 2; ++ni)
#pragma unroll
        for (int j = 0; j < 16; ++j) {
          float pv = __expf(s[ni][j] - newm);
          s[ni][j] = pv;
          rsum += pv;
        }
      rsum += __shfl_xor(rsum, 32, 64);
      lrun = lrun * corr + rsum;
#pragma unroll
      for (int i = 0; i < 16; ++i) { o[0][i] *= corr; o[1][i] *= corr; }

      // --- pack P to bf16 + permlane exchange -> PV B-frags; then PV MFMA
#pragma unroll
      for (int kbl = 0; kbl < 4; ++kbl) {
        const int ni = kbl >> 1, jb = (kbl & 1) * 8;
        int lo0 = cvtpk(s[ni][jb + 0], s[ni][jb + 1]);
        int lo1 = cvtpk(s[ni][jb + 2], s[ni][jb + 3]);
        int hi0 = cvtpk(s[ni][jb + 4], s[ni][jb + 5]);
        int hi1 = cvtpk(s[ni][jb + 6], s[ni][jb + 7]);
        asm("v_permlane32_swap_b32 %0, %1" : "+v"(lo0), "+v"(hi0));
        asm("v_permlane32_swap_b32 %0, %1" : "+v"(lo1), "+v"(hi1));
        i32x4 pw; pw[0] = lo0; pw[1] = lo1; pw[2] = hi0; pw[3] = hi1;
        bf16x8 pf = __builtin_bit_cast(bf16x8, pw);
        const int kb = st * 4 + kbl;          // 16-kk K-step index
#pragma unroll
        for (int mo = 0; mo < 2; ++mo) {
          int row = mo * 32 + r32;
          bf16x8 vf = *reinterpret_cast<const bf16x8*>(
              &VtB[row * 256 + ((kb * 32 + hi * 16) ^ ((row & 7) << 4))]);
          o[mo] = __builtin_amdgcn_mfma_f32_32x32x16_bf16(vf, pf, o[mo], 0, 0, 0);
        }
      }
    }
  }

  // epilogue: y[b][T][h*64 + d] = O^T[d][T] / lrun
  float inv = 1.0f / lrun;
#pragma unroll
  for (int mo = 0; mo < 2; ++mo)
#pragma unroll
    for (int rq = 0; rq < 4; ++rq) {
      bf16x4 ov;
#pragma unroll
      for (int c = 0; c < 4; ++c) ov[c] = f2bf(o[mo][rq * 4 + c] * inv);
      *reinterpret_cast<bf16x4*>(
          &y[(size_t)(b * 4096 + T) * 1024 + h * 64 + mo * 32 + rq * 8 + hi * 4]) = ov;
    }
}

// ---------------- GEMM2: out = y @ W_proj + b (f32 out) ----------------
__global__ __launch_bounds__(256) void k_gemm_out(const short* __restrict__ A,
                                                  const short* __restrict__ BT,
                                                  const float* __restrict__ bias,
                                                  float* __restrict__ C) {
  __shared__ short As[128][40];
  __shared__ short Bs[128][40];
  const int tid = threadIdx.x, lane = tid & 63, w = tid >> 6;
  const int wm = w >> 1, wn = w & 1;
  const int r16 = lane & 15, g4 = lane >> 4;
  const int m0 = blockIdx.x * 128, n0 = blockIdx.y * 128;
  f32x4 acc[4][4];
#pragma unroll
  for (int i = 0; i < 4; ++i)
#pragma unroll
    for (int j = 0; j < 4; ++j) acc[i][j] = f32x4{0.f, 0.f, 0.f, 0.f};
  for (int k0 = 0; k0 < 1024; k0 += 32) {
#pragma unroll
    for (int it = 0; it < 2; ++it) {
      int slot = tid + it * 256;
      int row = slot >> 2, dg = slot & 3;
      *reinterpret_cast<bf16x8*>(&As[row][dg * 8]) =
          *reinterpret_cast<const bf16x8*>(&A[(size_t)(m0 + row) * 1024 + k0 + dg * 8]);
      *reinterpret_cast<bf16x8*>(&Bs[row][dg * 8]) =
          *reinterpret_cast<const bf16x8*>(&BT[(size_t)(n0 + row) * 1024 + k0 + dg * 8]);
    }
    __syncthreads();
    bf16x8 af[4], bfr[4];
#pragma unroll
    for (int i = 0; i < 4; ++i)
      af[i] = *reinterpret_cast<const bf16x8*>(&As[wm * 64 + i * 16 + r16][g4 * 8]);
#pragma unroll
    for (int j = 0; j < 4; ++j)
      bfr[j] = *reinterpret_cast<const bf16x8*>(&Bs[wn * 64 + j * 16 + r16][g4 * 8]);
#pragma unroll
    for (int i = 0; i < 4; ++i)
#pragma unroll
      for (int j = 0; j < 4; ++j)
        acc[i][j] = __builtin_amdgcn_mfma_f32_16x16x32_bf16(af[i], bfr[j], acc[i][j], 0, 0, 0);
    __syncthreads();
  }
#pragma unroll
  for (int i = 0; i < 4; ++i)
#pragma unroll
    for (int j = 0; j < 4; ++j) {
      int row = m0 + wm * 64 + i * 16 + g4 * 4;
      int col = n0 + wn * 64 + j * 16 + r16;
      float bv = bias[col];
#pragma unroll
      for (int q = 0; q < 4; ++q)
        C[(size_t)(row + q) * 1024 + col] = acc[i][j][q] + bv;
    }
}

extern "C" void kernel_launch(void* const* d_in, const int* in_sizes, int n_in,
                              void* d_out, int out_size, void* d_ws, size_t ws_size,
                              hipStream_t stream) {
  const float* x      = (const float*)d_in[0];
  const float* W_attn = (const float*)d_in[1];
  const float* b_attn = (const float*)d_in[2];
  const float* W_proj = (const float*)d_in[3];
  const float* b_proj = (const float*)d_in[4];
  const float* E      = (const float*)d_in[5];
  const float* F      = (const float*)d_in[6];
  float* out = (float*)d_out;

  char* ws = (char*)d_ws;
  short* xb  = (short*)(ws + 0);          //  32 MB: x bf16            (16384x1024)
  short* WaT = (short*)(ws + 33554432);   //   6 MB: W_attn^T bf16     (3072x1024)
  short* WpT = (short*)(ws + 39845888);   //   2 MB: W_proj^T bf16     (1024x1024)
  short* Et  = (short*)(ws + 41943040);   //   8 MB: E^T bf16          (1024x4096)
  short* Ft  = (short*)(ws + 50331648);   //   8 MB: F^T bf16          (1024x4096)
  short* qb  = (short*)(ws + 58720256);   //  32 MB: q bf16            (16384x1024)
  short* kT  = (short*)(ws + 92274688);   //  32 MB: k^T bf16          (4x1024x4096)
  short* vT  = (short*)(ws + 125829120);  //  32 MB: v^T bf16          (4x1024x4096)
  short* kp  = (short*)(ws + 159383552);  //   8 MB: k_proj bf16       (4x1024x1024)
  short* vpt = (short*)(ws + 167772160);  //   8 MB: v_proj^T bf16     (4x1024x1024)
  short* yb  = (short*)(ws + 176160768);  //  32 MB: attn out bf16     (16384x1024)

  k_convert<<<16384, 256, 0, stream>>>(x, xb, 16777216);
  k_transpose_cvt<<<dim3(96, 32), 256, 0, stream>>>(W_attn, WaT, 1024, 3072);
  k_transpose_cvt<<<dim3(32, 32), 256, 0, stream>>>(W_proj, WpT, 1024, 1024);
  k_transpose_cvt<<<dim3(32, 128), 256, 0, stream>>>(E, Et, 4096, 1024);
  k_transpose_cvt<<<dim3(32, 128), 256, 0, stream>>>(F, Ft, 4096, 1024);

  k_gemm_qkv<<<dim3(128, 24), 256, 0, stream>>>(xb, WaT, b_attn, qb, kT, vT);
  k_proj<<<dim3(8, 8, 8), 256, 0, stream>>>(Et, Ft, kT, vT, kp, vpt);
  k_attn<<<dim3(32, 64), 256, 0, stream>>>(qb, kp, vpt, yb);
  k_gemm_out<<<dim3(128, 8), 256, 0, stream>>>(yb, WpT, b_proj, out);
}

// Round 5
// 458.778 us; speedup vs baseline: 1.4458x; 1.0821x over previous
//
#include <hip/hip_runtime.h>
#include <stdint.h>

typedef short bf16x8 __attribute__((ext_vector_type(8)));
typedef short bf16x4 __attribute__((ext_vector_type(4)));
typedef float f32x4 __attribute__((ext_vector_type(4)));
typedef float f32x16 __attribute__((ext_vector_type(16)));
typedef int i32x4 __attribute__((ext_vector_type(4)));

__device__ __forceinline__ short f2bf(float f) {
  union { float f; uint32_t u; } v; v.f = f;
  uint32_t r = (v.u + 0x7FFFu + ((v.u >> 16) & 1u)) >> 16;
  return (short)(uint16_t)r;
}

__device__ __forceinline__ int cvtpk(float lo, float hi) {
  int r;
  asm("v_cvt_pk_bf16_f32 %0, %1, %2" : "=v"(r) : "v"(lo), "v"(hi));
  return r;
}

// async global->LDS, 16B per lane; LDS dest must be linear in lane order
__device__ __forceinline__ void gload16(const void* g, void* l) {
  __builtin_amdgcn_global_load_lds(
      (const __attribute__((address_space(1))) unsigned int*)g,
      (__attribute__((address_space(3))) unsigned int*)l, 16, 0, 0);
}

// ---------------- elementwise f32 -> bf16 ----------------
__global__ __launch_bounds__(256) void k_convert(const float* __restrict__ in,
                                                 short* __restrict__ out, int n) {
  int i = (blockIdx.x * 256 + threadIdx.x) * 4;
  if (i >= n) return;
  float4 v = *reinterpret_cast<const float4*>(in + i);
  bf16x4 o; o[0] = f2bf(v.x); o[1] = f2bf(v.y); o[2] = f2bf(v.z); o[3] = f2bf(v.w);
  *reinterpret_cast<bf16x4*>(out + i) = o;
}

// ---------------- transpose + convert: out[C][R] = bf16(in[R][C]) ----------------
__global__ __launch_bounds__(256) void k_transpose_cvt(const float* __restrict__ in,
                                                       short* __restrict__ out,
                                                       int R, int C) {
  __shared__ float tile[32][33];
  int r0 = blockIdx.y * 32, c0 = blockIdx.x * 32;
  int tx = threadIdx.x & 31, ty = threadIdx.x >> 5;
#pragma unroll
  for (int j = 0; j < 4; ++j)
    tile[ty + j * 8][tx] = in[(size_t)(r0 + ty + j * 8) * C + c0 + tx];
  __syncthreads();
#pragma unroll
  for (int j = 0; j < 4; ++j)
    out[(size_t)(c0 + ty + j * 8) * R + r0 + tx] = f2bf(tile[tx][ty + j * 8]);
}

// ---------------- GEMM1: qkv = x @ W_attn + b ----------------
// q part -> qb[16384][1024] row-major; k,v parts -> kT/vT[b][c][t] (transposed)
__global__ __launch_bounds__(256) void k_gemm_qkv(const short* __restrict__ A,
                                                  const short* __restrict__ BT,
                                                  const float* __restrict__ bias,
                                                  short* __restrict__ qb,
                                                  short* __restrict__ kT,
                                                  short* __restrict__ vT) {
  __shared__ __align__(16) short As[128][32];
  __shared__ __align__(16) short Bs[128][32];
  const int tid = threadIdx.x, lane = tid & 63, w = tid >> 6;
  const int wm = w >> 1, wn = w & 1;
  const int r16 = lane & 15, g4 = lane >> 4;
  const int m0 = blockIdx.x * 128, n0 = blockIdx.y * 128;
  const int srow = tid >> 2, sdg = tid & 3;          // staging slot (it=0)
  const int srow1 = srow + 64;                       // staging slot (it=1)
  f32x4 acc[4][4];
#pragma unroll
  for (int i = 0; i < 4; ++i)
#pragma unroll
    for (int j = 0; j < 4; ++j) acc[i][j] = f32x4{0.f, 0.f, 0.f, 0.f};
  for (int k0 = 0; k0 < 1024; k0 += 32) {
    gload16(&A[(size_t)(m0 + srow) * 1024 + k0 + sdg * 8], &As[srow][sdg * 8]);
    gload16(&A[(size_t)(m0 + srow1) * 1024 + k0 + sdg * 8], &As[srow1][sdg * 8]);
    gload16(&BT[(size_t)(n0 + srow) * 1024 + k0 + sdg * 8], &Bs[srow][sdg * 8]);
    gload16(&BT[(size_t)(n0 + srow1) * 1024 + k0 + sdg * 8], &Bs[srow1][sdg * 8]);
    __syncthreads();
    bf16x8 af[4], bfr[4];
#pragma unroll
    for (int i = 0; i < 4; ++i)
      af[i] = *reinterpret_cast<const bf16x8*>(&As[wm * 64 + i * 16 + r16][g4 * 8]);
#pragma unroll
    for (int j = 0; j < 4; ++j)
      bfr[j] = *reinterpret_cast<const bf16x8*>(&Bs[wn * 64 + j * 16 + r16][g4 * 8]);
#pragma unroll
    for (int i = 0; i < 4; ++i)
#pragma unroll
      for (int j = 0; j < 4; ++j)
        acc[i][j] = __builtin_amdgcn_mfma_f32_16x16x32_bf16(af[i], bfr[j], acc[i][j], 0, 0, 0);
    __syncthreads();
  }
  const int seg = n0 >> 10;  // 0=q, 1=k, 2=v (blocks never straddle segments)
#pragma unroll
  for (int i = 0; i < 4; ++i)
#pragma unroll
    for (int j = 0; j < 4; ++j) {
      int row = m0 + wm * 64 + i * 16 + g4 * 4;
      int colg = n0 + wn * 64 + j * 16 + r16;
      float bv = bias[colg];
      if (seg == 0) {
#pragma unroll
        for (int q = 0; q < 4; ++q)
          qb[(size_t)(row + q) * 1024 + colg] = f2bf(acc[i][j][q] + bv);
      } else {
        int c = colg & 1023;
        int bb = row >> 12, t = row & 4095;
        short* dst = (seg == 1) ? kT : vT;
        bf16x4 ov;
#pragma unroll
        for (int q = 0; q < 4; ++q) ov[q] = f2bf(acc[i][j][q] + bv);
        *reinterpret_cast<bf16x4*>(&dst[((size_t)(bb << 10) + c) * 4096 + t]) = ov;
      }
    }
}

// ---------------- Projection (both operands t-contiguous) ----------------
// which=0: kp[b][kk][c] = (sum_t Et[kk][t]*kT[b][c][t]) / 8
// which=1: vpt[b][c][kk] = sum_t Ft[kk][t]*vT[b][c][t]   (transposed store)
__global__ __launch_bounds__(256) void k_proj(const short* __restrict__ Et,
                                              const short* __restrict__ Ft,
                                              const short* __restrict__ kT,
                                              const short* __restrict__ vT,
                                              short* __restrict__ kp,
                                              short* __restrict__ vpt) {
  const int z = blockIdx.z, b = z >> 1, which = z & 1;
  const short* __restrict__ AT = which ? Ft : Et;
  const short* __restrict__ BT = (which ? vT : kT) + ((size_t)b << 10) * 4096;
  __shared__ __align__(16) short As[128][32];
  __shared__ __align__(16) short Bs[128][32];
  const int tid = threadIdx.x, lane = tid & 63, w = tid >> 6;
  const int wm = w >> 1, wn = w & 1;
  const int r16 = lane & 15, g4 = lane >> 4;
  const int m0 = blockIdx.x * 128, n0 = blockIdx.y * 128;
  const int srow = tid >> 2, sdg = tid & 3;
  const int srow1 = srow + 64;
  f32x4 acc[4][4];
#pragma unroll
  for (int i = 0; i < 4; ++i)
#pragma unroll
    for (int j = 0; j < 4; ++j) acc[i][j] = f32x4{0.f, 0.f, 0.f, 0.f};
  for (int t0 = 0; t0 < 4096; t0 += 32) {
    gload16(&AT[(size_t)(m0 + srow) * 4096 + t0 + sdg * 8], &As[srow][sdg * 8]);
    gload16(&AT[(size_t)(m0 + srow1) * 4096 + t0 + sdg * 8], &As[srow1][sdg * 8]);
    gload16(&BT[(size_t)(n0 + srow) * 4096 + t0 + sdg * 8], &Bs[srow][sdg * 8]);
    gload16(&BT[(size_t)(n0 + srow1) * 4096 + t0 + sdg * 8], &Bs[srow1][sdg * 8]);
    __syncthreads();
    bf16x8 af[4], bfr[4];
#pragma unroll
    for (int i = 0; i < 4; ++i)
      af[i] = *reinterpret_cast<const bf16x8*>(&As[wm * 64 + i * 16 + r16][g4 * 8]);
#pragma unroll
    for (int j = 0; j < 4; ++j)
      bfr[j] = *reinterpret_cast<const bf16x8*>(&Bs[wn * 64 + j * 16 + r16][g4 * 8]);
#pragma unroll
    for (int i = 0; i < 4; ++i)
#pragma unroll
      for (int j = 0; j < 4; ++j)
        acc[i][j] = __builtin_amdgcn_mfma_f32_16x16x32_bf16(af[i], bfr[j], acc[i][j], 0, 0, 0);
    __syncthreads();
  }
  if (which) {
#pragma unroll
    for (int i = 0; i < 4; ++i)
#pragma unroll
      for (int j = 0; j < 4; ++j) {
        int row = m0 + wm * 64 + i * 16 + g4 * 4;   // kk
        int col = n0 + wn * 64 + j * 16 + r16;      // c
        bf16x4 ov;
#pragma unroll
        for (int q = 0; q < 4; ++q) ov[q] = f2bf(acc[i][j][q]);
        *reinterpret_cast<bf16x4*>(&vpt[((size_t)(b * 1024) + col) * 1024 + row]) = ov;
      }
  } else {
#pragma unroll
    for (int i = 0; i < 4; ++i)
#pragma unroll
      for (int j = 0; j < 4; ++j) {
        int row = m0 + wm * 64 + i * 16 + g4 * 4;
        int col = n0 + wn * 64 + j * 16 + r16;
#pragma unroll
        for (int q = 0; q < 4; ++q)
          kp[((size_t)(b * 1024) + row + q) * 1024 + col] = f2bf(acc[i][j][q] * 0.125f);
      }
  }
}

// ---------------- Flash attention: swapped 32x32x16 MFMA, in-register P ----------------
__global__ __launch_bounds__(256, 3) void k_attn(const short* __restrict__ qb,
                                                 const short* __restrict__ kp,
                                                 const short* __restrict__ vpt,
                                                 short* __restrict__ y) {
  __shared__ __align__(16) char KsB[128 * 128];   // [kk][d] swizzled, 16 KB
  __shared__ __align__(16) char VtB[64 * 256];    // [d][kk] swizzled, 16 KB
  const int tid = threadIdx.x, lane = tid & 63, w = tid >> 6;
  const int r32 = lane & 31, hi = lane >> 5;
  const int iblk = blockIdx.x;
  const int bh = blockIdx.y, b = bh >> 4, h = bh & 15;
  const int t0 = iblk * 128;
  const int tl = w * 32 + r32;          // local row
  const int T = t0 + tl;                // global row (within b)

  bf16x8 qf[4];
#pragma unroll
  for (int kd = 0; kd < 4; ++kd)
    qf[kd] = *reinterpret_cast<const bf16x8*>(
        &qb[(size_t)(b * 4096 + T) * 1024 + h * 64 + kd * 16 + hi * 8]);

  f32x16 o[2];
#pragma unroll
  for (int i = 0; i < 16; ++i) { o[0][i] = 0.f; o[1][i] = 0.f; }
  float mrun = -1e30f, lrun = 0.f;

  const short* kpb = kp + ((size_t)b << 20) + h * 64;             // [kk][c]
  const short* vtb = vpt + (((size_t)b << 10) + h * 64) * 1024;   // [c][kk]

  const int ntiles = (iblk + 1 < 8) ? (iblk + 1) : 8;
  for (int jt = 0; jt < ntiles; ++jt) {
    const int kk0 = jt * 128;
    __syncthreads();
#pragma unroll
    for (int it = 0; it < 4; ++it) {
      int slot = tid + it * 256;
      int kk = slot >> 3, c8 = slot & 7;
      bf16x8 kv = *reinterpret_cast<const bf16x8*>(&kpb[(size_t)(kk0 + kk) * 1024 + c8 * 8]);
      *reinterpret_cast<bf16x8*>(&KsB[kk * 128 + ((c8 * 16) ^ ((kk & 7) << 4))]) = kv;
      int d = slot >> 4, c16 = slot & 15;
      bf16x8 vv = *reinterpret_cast<const bf16x8*>(&vtb[(size_t)d * 1024 + kk0 + c16 * 8]);
      *reinterpret_cast<bf16x8*>(&VtB[d * 256 + ((c16 * 16) ^ ((d & 7) << 4))]) = vv;
    }
    __syncthreads();

#pragma unroll
    for (int st = 0; st < 2; ++st) {          // 64-kk sub-tiles
      f32x16 s[2];
#pragma unroll
      for (int i = 0; i < 16; ++i) { s[0][i] = 0.f; s[1][i] = 0.f; }
#pragma unroll
      for (int ni = 0; ni < 2; ++ni) {
        int n = st * 2 + ni;
#pragma unroll
        for (int kd = 0; kd < 4; ++kd) {
          int row = n * 32 + r32;
          bf16x8 kf = *reinterpret_cast<const bf16x8*>(
              &KsB[row * 128 + ((kd * 32 + hi * 16) ^ ((row & 7) << 4))]);
          s[ni] = __builtin_amdgcn_mfma_f32_32x32x16_bf16(kf, qf[kd], s[ni], 0, 0, 0);
        }
      }

      if (jt == iblk) {  // causal mask on diagonal tile
#pragma unroll
        for (int ni = 0; ni < 2; ++ni)
#pragma unroll
          for (int j = 0; j < 16; ++j) {
            int kkl = (st * 2 + ni) * 32 + (j & 3) + 8 * (j >> 2) + 4 * hi;
            if (kkl > tl) s[ni][j] = -1e30f;
          }
      }

      float pmax = s[0][0];
#pragma unroll
      for (int j = 1; j < 16; ++j) pmax = fmaxf(pmax, s[0][j]);
#pragma unroll
      for (int j = 0; j < 16; ++j) pmax = fmaxf(pmax, s[1][j]);
      pmax = fmaxf(pmax, __shfl_xor(pmax, 32, 64));
      float newm = fmaxf(mrun, pmax);
      float corr = __expf(mrun - newm);
      mrun = newm;
      float rsum = 0.f;
#pragma unroll
      for (int ni = 0; ni < 2; ++ni)
#pragma unroll
        for (int j = 0; j < 16; ++j) {
          float pv = __expf(s[ni][j] - newm);
          s[ni][j] = pv;
          rsum += pv;
        }
      rsum += __shfl_xor(rsum, 32, 64);
      lrun = lrun * corr + rsum;
#pragma unroll
      for (int i = 0; i < 16; ++i) { o[0][i] *= corr; o[1][i] *= corr; }

#pragma unroll
      for (int kbl = 0; kbl < 4; ++kbl) {
        const int ni = kbl >> 1, jb = (kbl & 1) * 8;
        int lo0 = cvtpk(s[ni][jb + 0], s[ni][jb + 1]);
        int lo1 = cvtpk(s[ni][jb + 2], s[ni][jb + 3]);
        int hi0 = cvtpk(s[ni][jb + 4], s[ni][jb + 5]);
        int hi1 = cvtpk(s[ni][jb + 6], s[ni][jb + 7]);
        asm("v_permlane32_swap_b32 %0, %1" : "+v"(lo0), "+v"(hi0));
        asm("v_permlane32_swap_b32 %0, %1" : "+v"(lo1), "+v"(hi1));
        i32x4 pw; pw[0] = lo0; pw[1] = lo1; pw[2] = hi0; pw[3] = hi1;
        bf16x8 pf = __builtin_bit_cast(bf16x8, pw);
        const int kb = st * 4 + kbl;
#pragma unroll
        for (int mo = 0; mo < 2; ++mo) {
          int row = mo * 32 + r32;
          bf16x8 vf = *reinterpret_cast<const bf16x8*>(
              &VtB[row * 256 + ((kb * 32 + hi * 16) ^ ((row & 7) << 4))]);
          o[mo] = __builtin_amdgcn_mfma_f32_32x32x16_bf16(vf, pf, o[mo], 0, 0, 0);
        }
      }
    }
  }

  float inv = 1.0f / lrun;
#pragma unroll
  for (int mo = 0; mo < 2; ++mo)
#pragma unroll
    for (int rq = 0; rq < 4; ++rq) {
      bf16x4 ov;
#pragma unroll
      for (int c = 0; c < 4; ++c) ov[c] = f2bf(o[mo][rq * 4 + c] * inv);
      *reinterpret_cast<bf16x4*>(
          &y[(size_t)(b * 4096 + T) * 1024 + h * 64 + mo * 32 + rq * 8 + hi * 4]) = ov;
    }
}

// ---------------- GEMM2: out = y @ W_proj + b (f32 out) ----------------
__global__ __launch_bounds__(256) void k_gemm_out(const short* __restrict__ A,
                                                  const short* __restrict__ BT,
                                                  const float* __restrict__ bias,
                                                  float* __restrict__ C) {
  __shared__ __align__(16) short As[128][32];
  __shared__ __align__(16) short Bs[128][32];
  const int tid = threadIdx.x, lane = tid & 63, w = tid >> 6;
  const int wm = w >> 1, wn = w & 1;
  const int r16 = lane & 15, g4 = lane >> 4;
  const int m0 = blockIdx.x * 128, n0 = blockIdx.y * 128;
  const int srow = tid >> 2, sdg = tid & 3;
  const int srow1 = srow + 64;
  f32x4 acc[4][4];
#pragma unroll
  for (int i = 0; i < 4; ++i)
#pragma unroll
    for (int j = 0; j < 4; ++j) acc[i][j] = f32x4{0.f, 0.f, 0.f, 0.f};
  for (int k0 = 0; k0 < 1024; k0 += 32) {
    gload16(&A[(size_t)(m0 + srow) * 1024 + k0 + sdg * 8], &As[srow][sdg * 8]);
    gload16(&A[(size_t)(m0 + srow1) * 1024 + k0 + sdg * 8], &As[srow1][sdg * 8]);
    gload16(&BT[(size_t)(n0 + srow) * 1024 + k0 + sdg * 8], &Bs[srow][sdg * 8]);
    gload16(&BT[(size_t)(n0 + srow1) * 1024 + k0 + sdg * 8], &Bs[srow1][sdg * 8]);
    __syncthreads();
    bf16x8 af[4], bfr[4];
#pragma unroll
    for (int i = 0; i < 4; ++i)
      af[i] = *reinterpret_cast<const bf16x8*>(&As[wm * 64 + i * 16 + r16][g4 * 8]);
#pragma unroll
    for (int j = 0; j < 4; ++j)
      bfr[j] = *reinterpret_cast<const bf16x8*>(&Bs[wn * 64 + j * 16 + r16][g4 * 8]);
#pragma unroll
    for (int i = 0; i < 4; ++i)
#pragma unroll
      for (int j = 0; j < 4; ++j)
        acc[i][j] = __builtin_amdgcn_mfma_f32_16x16x32_bf16(af[i], bfr[j], acc[i][j], 0, 0, 0);
    __syncthreads();
  }
#pragma unroll
  for (int i = 0; i < 4; ++i)
#pragma unroll
    for (int j = 0; j < 4; ++j) {
      int row = m0 + wm * 64 + i * 16 + g4 * 4;
      int col = n0 + wn * 64 + j * 16 + r16;
      float bv = bias[col];
#pragma unroll
      for (int q = 0; q < 4; ++q)
        C[(size_t)(row + q) * 1024 + col] = acc[i][j][q] + bv;
    }
}

extern "C" void kernel_launch(void* const* d_in, const int* in_sizes, int n_in,
                              void* d_out, int out_size, void* d_ws, size_t ws_size,
                              hipStream_t stream) {
  const float* x      = (const float*)d_in[0];
  const float* W_attn = (const float*)d_in[1];
  const float* b_attn = (const float*)d_in[2];
  const float* W_proj = (const float*)d_in[3];
  const float* b_proj = (const float*)d_in[4];
  const float* E      = (const float*)d_in[5];
  const float* F      = (const float*)d_in[6];
  float* out = (float*)d_out;

  char* ws = (char*)d_ws;
  short* xb  = (short*)(ws + 0);          //  32 MB: x bf16            (16384x1024)
  short* WaT = (short*)(ws + 33554432);   //   6 MB: W_attn^T bf16     (3072x1024)
  short* WpT = (short*)(ws + 39845888);   //   2 MB: W_proj^T bf16     (1024x1024)
  short* Et  = (short*)(ws + 41943040);   //   8 MB: E^T bf16          (1024x4096)
  short* Ft  = (short*)(ws + 50331648);   //   8 MB: F^T bf16          (1024x4096)
  short* qb  = (short*)(ws + 58720256);   //  32 MB: q bf16            (16384x1024)
  short* kT  = (short*)(ws + 92274688);   //  32 MB: k^T bf16          (4x1024x4096)
  short* vT  = (short*)(ws + 125829120);  //  32 MB: v^T bf16          (4x1024x4096)
  short* kp  = (short*)(ws + 159383552);  //   8 MB: k_proj bf16       (4x1024x1024)
  short* vpt = (short*)(ws + 167772160);  //   8 MB: v_proj^T bf16     (4x1024x1024)
  short* yb  = (short*)(ws + 176160768);  //  32 MB: attn out bf16     (16384x1024)

  k_convert<<<16384, 256, 0, stream>>>(x, xb, 16777216);
  k_transpose_cvt<<<dim3(96, 32), 256, 0, stream>>>(W_attn, WaT, 1024, 3072);
  k_transpose_cvt<<<dim3(32, 32), 256, 0, stream>>>(W_proj, WpT, 1024, 1024);
  k_transpose_cvt<<<dim3(32, 128), 256, 0, stream>>>(E, Et, 4096, 1024);
  k_transpose_cvt<<<dim3(32, 128), 256, 0, stream>>>(F, Ft, 4096, 1024);

  k_gemm_qkv<<<dim3(128, 24), 256, 0, stream>>>(xb, WaT, b_attn, qb, kT, vT);
  k_proj<<<dim3(8, 8, 8), 256, 0, stream>>>(Et, Ft, kT, vT, kp, vpt);
  k_attn<<<dim3(32, 64), 256, 0, stream>>>(qb, kp, vpt, yb);
  k_gemm_out<<<dim3(128, 8), 256, 0, stream>>>(yb, WpT, b_proj, out);
}

// Round 6
// 441.247 us; speedup vs baseline: 1.5033x; 1.0397x over previous
//
#include <hip/hip_runtime.h>
#include <stdint.h>

typedef short bf16x8 __attribute__((ext_vector_type(8)));
typedef short bf16x4 __attribute__((ext_vector_type(4)));
typedef float f32x4 __attribute__((ext_vector_type(4)));
typedef float f32x16 __attribute__((ext_vector_type(16)));
typedef int i32x4 __attribute__((ext_vector_type(4)));

__device__ __forceinline__ short f2bf(float f) {
  union { float f; uint32_t u; } v; v.f = f;
  uint32_t r = (v.u + 0x7FFFu + ((v.u >> 16) & 1u)) >> 16;
  return (short)(uint16_t)r;
}

__device__ __forceinline__ int cvtpk(float lo, float hi) {
  int r;
  asm("v_cvt_pk_bf16_f32 %0, %1, %2" : "=v"(r) : "v"(lo), "v"(hi));
  return r;
}

// async global->LDS, 16B per lane; LDS dest must be linear in lane order
__device__ __forceinline__ void gload16(const void* g, void* l) {
  __builtin_amdgcn_global_load_lds(
      (const __attribute__((address_space(1))) unsigned int*)g,
      (__attribute__((address_space(3))) unsigned int*)l, 16, 0, 0);
}

// ---------------- elementwise f32 -> bf16 ----------------
__global__ __launch_bounds__(256) void k_convert(const float* __restrict__ in,
                                                 short* __restrict__ out, int n) {
  int i = (blockIdx.x * 256 + threadIdx.x) * 4;
  if (i >= n) return;
  float4 v = *reinterpret_cast<const float4*>(in + i);
  bf16x4 o; o[0] = f2bf(v.x); o[1] = f2bf(v.y); o[2] = f2bf(v.z); o[3] = f2bf(v.w);
  *reinterpret_cast<bf16x4*>(out + i) = o;
}

// ---------------- transpose + convert: out[C][R] = bf16(in[R][C]) ----------------
__global__ __launch_bounds__(256) void k_transpose_cvt(const float* __restrict__ in,
                                                       short* __restrict__ out,
                                                       int R, int C) {
  __shared__ float tile[32][33];
  int r0 = blockIdx.y * 32, c0 = blockIdx.x * 32;
  int tx = threadIdx.x & 31, ty = threadIdx.x >> 5;
#pragma unroll
  for (int j = 0; j < 4; ++j)
    tile[ty + j * 8][tx] = in[(size_t)(r0 + ty + j * 8) * C + c0 + tx];
  __syncthreads();
#pragma unroll
  for (int j = 0; j < 4; ++j)
    out[(size_t)(c0 + ty + j * 8) * R + r0 + tx] = f2bf(tile[tx][ty + j * 8]);
}

// ---------------- GEMM1: qkv = x @ W_attn + b  (256x256 tile, BK=64, 8 waves) ----------
// q part -> qb[16384][1024] row-major; k,v parts -> kT/vT[b][c][t] (transposed)
// LDS: double-buffered 256x64 bf16 tiles for A and B^T, XOR-swizzled
// (physical 16B-slot s of row r holds logical slot s ^ (r&7); gload_lds dest is
//  linear, the inverse swizzle is applied on the GLOBAL source address).
__global__ __launch_bounds__(512, 2) void k_gemm_qkv(const short* __restrict__ A,
                                                     const short* __restrict__ BT,
                                                     const float* __restrict__ bias,
                                                     short* __restrict__ qb,
                                                     short* __restrict__ kT,
                                                     short* __restrict__ vT) {
  __shared__ __align__(16) short sA[2][256 * 64];   // 64 KB
  __shared__ __align__(16) short sB[2][256 * 64];   // 64 KB
  char* sAc = (char*)&sA[0][0];
  char* sBc = (char*)&sB[0][0];
  const int tid = threadIdx.x, l = tid & 63, wv = tid >> 6;
  const int wm = wv >> 2, wn = wv & 3;   // 2 (M) x 4 (N) waves; per-wave 128x64 out
  const int r16 = l & 15, g4 = l >> 4;
  // bijective XCD swizzle: 768 blocks, 96 per XCD, m-tile fastest within an XCD
  const int orig = blockIdx.x;
  const int wg = (orig & 7) * 96 + (orig >> 3);
  const int m0 = (wg & 63) * 256, n0 = (wg >> 6) * 256;
  // staging geometry: 64 regions of 1KB (8 rows x 8 slots); region g = i*8 + wv
  const int rl = l >> 3, sl = (l & 7) ^ rl;   // inverse-swizzled source slot
  const short* aS = A + (size_t)(m0 + wv * 8 + rl) * 1024 + sl * 8;
  const short* bS = BT + (size_t)(n0 + wv * 8 + rl) * 1024 + sl * 8;
  const int ldst = wv * 1024 + l * 16;

  f32x4 acc[8][4];
#pragma unroll
  for (int i = 0; i < 8; ++i)
#pragma unroll
    for (int j = 0; j < 4; ++j) acc[i][j] = f32x4{0.f, 0.f, 0.f, 0.f};

#define STAGE_QKV(kt, bf)                                                        \
  {                                                                              \
    const int k0_ = (kt) * 64;                                                   \
    _Pragma("unroll") for (int i = 0; i < 4; ++i) {                              \
      gload16(aS + (size_t)i * 64 * 1024 + k0_, sAc + (bf) * 32768 + i * 8192 + ldst); \
      gload16(bS + (size_t)i * 64 * 1024 + k0_, sBc + (bf) * 32768 + i * 8192 + ldst); \
    }                                                                            \
  }

  STAGE_QKV(0, 0);
  asm volatile("s_waitcnt vmcnt(0)" ::: "memory");
  __builtin_amdgcn_s_barrier();
  asm volatile("" ::: "memory");

  for (int kt = 0; kt < 16; ++kt) {
    const int cur = kt & 1;
    if (kt + 1 < 16) STAGE_QKV(kt + 1, cur ^ 1);
    const char* aT = sAc + cur * 32768;
    const char* bT = sBc + cur * 32768;
#pragma unroll
    for (int ph = 0; ph < 4; ++ph) {
      const int mh = ph >> 1, nh = ph & 1;
      bf16x8 af[4][2], bfr[2][2];
#pragma unroll
      for (int mi = 0; mi < 4; ++mi)
#pragma unroll
        for (int ks = 0; ks < 2; ++ks) {
          int row = wm * 128 + mh * 64 + mi * 16 + r16;
          af[mi][ks] = *(const bf16x8*)(aT + row * 128 + (((ks * 4 + g4) ^ (r16 & 7)) * 16));
        }
#pragma unroll
      for (int ni = 0; ni < 2; ++ni)
#pragma unroll
        for (int ks = 0; ks < 2; ++ks) {
          int row = wn * 64 + nh * 32 + ni * 16 + r16;
          bfr[ni][ks] = *(const bf16x8*)(bT + row * 128 + (((ks * 4 + g4) ^ (r16 & 7)) * 16));
        }
      __builtin_amdgcn_s_setprio(1);
#pragma unroll
      for (int ks = 0; ks < 2; ++ks)
#pragma unroll
        for (int mi = 0; mi < 4; ++mi)
#pragma unroll
          for (int ni = 0; ni < 2; ++ni)
            acc[mh * 4 + mi][nh * 2 + ni] = __builtin_amdgcn_mfma_f32_16x16x32_bf16(
                af[mi][ks], bfr[ni][ks], acc[mh * 4 + mi][nh * 2 + ni], 0, 0, 0);
      __builtin_amdgcn_s_setprio(0);
    }
    asm volatile("s_waitcnt vmcnt(0)" ::: "memory");
    __builtin_amdgcn_s_barrier();
    asm volatile("" ::: "memory");
  }
#undef STAGE_QKV

  const int seg = n0 >> 10;  // 0=q, 1=k, 2=v (256-col tiles never straddle)
#pragma unroll
  for (int i = 0; i < 8; ++i)
#pragma unroll
    for (int j = 0; j < 4; ++j) {
      int row = m0 + wm * 128 + i * 16 + g4 * 4;
      int colg = n0 + wn * 64 + j * 16 + r16;
      float bv = bias[colg];
      if (seg == 0) {
#pragma unroll
        for (int q = 0; q < 4; ++q)
          qb[(size_t)(row + q) * 1024 + colg] = f2bf(acc[i][j][q] + bv);
      } else {
        int c = colg & 1023;
        int bb = row >> 12, t = row & 4095;
        short* dst = (seg == 1) ? kT : vT;
        bf16x4 ov;
#pragma unroll
        for (int q = 0; q < 4; ++q) ov[q] = f2bf(acc[i][j][q] + bv);
        *reinterpret_cast<bf16x4*>(&dst[((size_t)(bb << 10) + c) * 4096 + t]) = ov;
      }
    }
}

// ---------------- Projection (both operands t-contiguous) ----------------
// which=0: kp[b][kk][c] = (sum_t Et[kk][t]*kT[b][c][t]) / 8
// which=1: vpt[b][c][kk] = sum_t Ft[kk][t]*vT[b][c][t]   (transposed store)
__global__ __launch_bounds__(256) void k_proj(const short* __restrict__ Et,
                                              const short* __restrict__ Ft,
                                              const short* __restrict__ kT,
                                              const short* __restrict__ vT,
                                              short* __restrict__ kp,
                                              short* __restrict__ vpt) {
  const int z = blockIdx.z, b = z >> 1, which = z & 1;
  const short* __restrict__ AT = which ? Ft : Et;
  const short* __restrict__ BT = (which ? vT : kT) + ((size_t)b << 10) * 4096;
  __shared__ __align__(16) short As[128][32];
  __shared__ __align__(16) short Bs[128][32];
  const int tid = threadIdx.x, lane = tid & 63, w = tid >> 6;
  const int wm = w >> 1, wn = w & 1;
  const int r16 = lane & 15, g4 = lane >> 4;
  const int m0 = blockIdx.x * 128, n0 = blockIdx.y * 128;
  const int srow = tid >> 2, sdg = tid & 3;
  const int srow1 = srow + 64;
  f32x4 acc[4][4];
#pragma unroll
  for (int i = 0; i < 4; ++i)
#pragma unroll
    for (int j = 0; j < 4; ++j) acc[i][j] = f32x4{0.f, 0.f, 0.f, 0.f};
  for (int t0 = 0; t0 < 4096; t0 += 32) {
    gload16(&AT[(size_t)(m0 + srow) * 4096 + t0 + sdg * 8], &As[srow][sdg * 8]);
    gload16(&AT[(size_t)(m0 + srow1) * 4096 + t0 + sdg * 8], &As[srow1][sdg * 8]);
    gload16(&BT[(size_t)(n0 + srow) * 4096 + t0 + sdg * 8], &Bs[srow][sdg * 8]);
    gload16(&BT[(size_t)(n0 + srow1) * 4096 + t0 + sdg * 8], &Bs[srow1][sdg * 8]);
    __syncthreads();
    bf16x8 af[4], bfr[4];
#pragma unroll
    for (int i = 0; i < 4; ++i)
      af[i] = *reinterpret_cast<const bf16x8*>(&As[wm * 64 + i * 16 + r16][g4 * 8]);
#pragma unroll
    for (int j = 0; j < 4; ++j)
      bfr[j] = *reinterpret_cast<const bf16x8*>(&Bs[wn * 64 + j * 16 + r16][g4 * 8]);
#pragma unroll
    for (int i = 0; i < 4; ++i)
#pragma unroll
      for (int j = 0; j < 4; ++j)
        acc[i][j] = __builtin_amdgcn_mfma_f32_16x16x32_bf16(af[i], bfr[j], acc[i][j], 0, 0, 0);
    __syncthreads();
  }
  if (which) {
#pragma unroll
    for (int i = 0; i < 4; ++i)
#pragma unroll
      for (int j = 0; j < 4; ++j) {
        int row = m0 + wm * 64 + i * 16 + g4 * 4;   // kk
        int col = n0 + wn * 64 + j * 16 + r16;      // c
        bf16x4 ov;
#pragma unroll
        for (int q = 0; q < 4; ++q) ov[q] = f2bf(acc[i][j][q]);
        *reinterpret_cast<bf16x4*>(&vpt[((size_t)(b * 1024) + col) * 1024 + row]) = ov;
      }
  } else {
#pragma unroll
    for (int i = 0; i < 4; ++i)
#pragma unroll
      for (int j = 0; j < 4; ++j) {
        int row = m0 + wm * 64 + i * 16 + g4 * 4;
        int col = n0 + wn * 64 + j * 16 + r16;
#pragma unroll
        for (int q = 0; q < 4; ++q)
          kp[((size_t)(b * 1024) + row + q) * 1024 + col] = f2bf(acc[i][j][q] * 0.125f);
      }
  }
}

// ---------------- Flash attention: swapped 32x32x16 MFMA, in-register P ----------------
__global__ __launch_bounds__(256, 3) void k_attn(const short* __restrict__ qb,
                                                 const short* __restrict__ kp,
                                                 const short* __restrict__ vpt,
                                                 short* __restrict__ y) {
  __shared__ __align__(16) char KsB[128 * 128];   // [kk][d] swizzled, 16 KB
  __shared__ __align__(16) char VtB[64 * 256];    // [d][kk] swizzled, 16 KB
  const int tid = threadIdx.x, lane = tid & 63, w = tid >> 6;
  const int r32 = lane & 31, hi = lane >> 5;
  const int iblk = blockIdx.x;
  const int bh = blockIdx.y, b = bh >> 4, h = bh & 15;
  const int t0 = iblk * 128;
  const int tl = w * 32 + r32;          // local row
  const int T = t0 + tl;                // global row (within b)

  bf16x8 qf[4];
#pragma unroll
  for (int kd = 0; kd < 4; ++kd)
    qf[kd] = *reinterpret_cast<const bf16x8*>(
        &qb[(size_t)(b * 4096 + T) * 1024 + h * 64 + kd * 16 + hi * 8]);

  f32x16 o[2];
#pragma unroll
  for (int i = 0; i < 16; ++i) { o[0][i] = 0.f; o[1][i] = 0.f; }
  float mrun = -1e30f, lrun = 0.f;

  const short* kpb = kp + ((size_t)b << 20) + h * 64;             // [kk][c]
  const short* vtb = vpt + (((size_t)b << 10) + h * 64) * 1024;   // [c][kk]

  const int ntiles = (iblk + 1 < 8) ? (iblk + 1) : 8;
  for (int jt = 0; jt < ntiles; ++jt) {
    const int kk0 = jt * 128;
    __syncthreads();
#pragma unroll
    for (int it = 0; it < 4; ++it) {
      int slot = tid + it * 256;
      int kk = slot >> 3, c8 = slot & 7;
      bf16x8 kv = *reinterpret_cast<const bf16x8*>(&kpb[(size_t)(kk0 + kk) * 1024 + c8 * 8]);
      *reinterpret_cast<bf16x8*>(&KsB[kk * 128 + ((c8 * 16) ^ ((kk & 7) << 4))]) = kv;
      int d = slot >> 4, c16 = slot & 15;
      bf16x8 vv = *reinterpret_cast<const bf16x8*>(&vtb[(size_t)d * 1024 + kk0 + c16 * 8]);
      *reinterpret_cast<bf16x8*>(&VtB[d * 256 + ((c16 * 16) ^ ((d & 7) << 4))]) = vv;
    }
    __syncthreads();

#pragma unroll
    for (int st = 0; st < 2; ++st) {          // 64-kk sub-tiles
      f32x16 s[2];
#pragma unroll
      for (int i = 0; i < 16; ++i) { s[0][i] = 0.f; s[1][i] = 0.f; }
#pragma unroll
      for (int ni = 0; ni < 2; ++ni) {
        int n = st * 2 + ni;
#pragma unroll
        for (int kd = 0; kd < 4; ++kd) {
          int row = n * 32 + r32;
          bf16x8 kf = *reinterpret_cast<const bf16x8*>(
              &KsB[row * 128 + ((kd * 32 + hi * 16) ^ ((row & 7) << 4))]);
          s[ni] = __builtin_amdgcn_mfma_f32_32x32x16_bf16(kf, qf[kd], s[ni], 0, 0, 0);
        }
      }

      if (jt == iblk) {  // causal mask on diagonal tile
#pragma unroll
        for (int ni = 0; ni < 2; ++ni)
#pragma unroll
          for (int j = 0; j < 16; ++j) {
            int kkl = (st * 2 + ni) * 32 + (j & 3) + 8 * (j >> 2) + 4 * hi;
            if (kkl > tl) s[ni][j] = -1e30f;
          }
      }

      float pmax = s[0][0];
#pragma unroll
      for (int j = 1; j < 16; ++j) pmax = fmaxf(pmax, s[0][j]);
#pragma unroll
      for (int j = 0; j < 16; ++j) pmax = fmaxf(pmax, s[1][j]);
      pmax = fmaxf(pmax, __shfl_xor(pmax, 32, 64));
      float newm = fmaxf(mrun, pmax);
      float corr = __expf(mrun - newm);
      mrun = newm;
      float rsum = 0.f;
#pragma unroll
      for (int ni = 0; ni < 2; ++ni)
#pragma unroll
        for (int j = 0; j < 16; ++j) {
          float pv = __expf(s[ni][j] - newm);
          s[ni][j] = pv;
          rsum += pv;
        }
      rsum += __shfl_xor(rsum, 32, 64);
      lrun = lrun * corr + rsum;
#pragma unroll
      for (int i = 0; i < 16; ++i) { o[0][i] *= corr; o[1][i] *= corr; }

#pragma unroll
      for (int kbl = 0; kbl < 4; ++kbl) {
        const int ni = kbl >> 1, jb = (kbl & 1) * 8;
        int lo0 = cvtpk(s[ni][jb + 0], s[ni][jb + 1]);
        int lo1 = cvtpk(s[ni][jb + 2], s[ni][jb + 3]);
        int hi0 = cvtpk(s[ni][jb + 4], s[ni][jb + 5]);
        int hi1 = cvtpk(s[ni][jb + 6], s[ni][jb + 7]);
        asm("v_permlane32_swap_b32 %0, %1" : "+v"(lo0), "+v"(hi0));
        asm("v_permlane32_swap_b32 %0, %1" : "+v"(lo1), "+v"(hi1));
        i32x4 pw; pw[0] = lo0; pw[1] = lo1; pw[2] = hi0; pw[3] = hi1;
        bf16x8 pf = __builtin_bit_cast(bf16x8, pw);
        const int kb = st * 4 + kbl;
#pragma unroll
        for (int mo = 0; mo < 2; ++mo) {
          int row = mo * 32 + r32;
          bf16x8 vf = *reinterpret_cast<const bf16x8*>(
              &VtB[row * 256 + ((kb * 32 + hi * 16) ^ ((row & 7) << 4))]);
          o[mo] = __builtin_amdgcn_mfma_f32_32x32x16_bf16(vf, pf, o[mo], 0, 0, 0);
        }
      }
    }
  }

  float inv = 1.0f / lrun;
#pragma unroll
  for (int mo = 0; mo < 2; ++mo)
#pragma unroll
    for (int rq = 0; rq < 4; ++rq) {
      bf16x4 ov;
#pragma unroll
      for (int c = 0; c < 4; ++c) ov[c] = f2bf(o[mo][rq * 4 + c] * inv);
      *reinterpret_cast<bf16x4*>(
          &y[(size_t)(b * 4096 + T) * 1024 + h * 64 + mo * 32 + rq * 8 + hi * 4]) = ov;
    }
}

// ---------------- GEMM2: out = y @ W_proj + b (f32 out) ----------------
__global__ __launch_bounds__(256) void k_gemm_out(const short* __restrict__ A,
                                                  const short* __restrict__ BT,
                                                  const float* __restrict__ bias,
                                                  float* __restrict__ C) {
  __shared__ __align__(16) short As[128][32];
  __shared__ __align__(16) short Bs[128][32];
  const int tid = threadIdx.x, lane = tid & 63, w = tid >> 6;
  const int wm = w >> 1, wn = w & 1;
  const int r16 = lane & 15, g4 = lane >> 4;
  const int m0 = blockIdx.x * 128, n0 = blockIdx.y * 128;
  const int srow = tid >> 2, sdg = tid & 3;
  const int srow1 = srow + 64;
  f32x4 acc[4][4];
#pragma unroll
  for (int i = 0; i < 4; ++i)
#pragma unroll
    for (int j = 0; j < 4; ++j) acc[i][j] = f32x4{0.f, 0.f, 0.f, 0.f};
  for (int k0 = 0; k0 < 1024; k0 += 32) {
    gload16(&A[(size_t)(m0 + srow) * 1024 + k0 + sdg * 8], &As[srow][sdg * 8]);
    gload16(&A[(size_t)(m0 + srow1) * 1024 + k0 + sdg * 8], &As[srow1][sdg * 8]);
    gload16(&BT[(size_t)(n0 + srow) * 1024 + k0 + sdg * 8], &Bs[srow][sdg * 8]);
    gload16(&BT[(size_t)(n0 + srow1) * 1024 + k0 + sdg * 8], &Bs[srow1][sdg * 8]);
    __syncthreads();
    bf16x8 af[4], bfr[4];
#pragma unroll
    for (int i = 0; i < 4; ++i)
      af[i] = *reinterpret_cast<const bf16x8*>(&As[wm * 64 + i * 16 + r16][g4 * 8]);
#pragma unroll
    for (int j = 0; j < 4; ++j)
      bfr[j] = *reinterpret_cast<const bf16x8*>(&Bs[wn * 64 + j * 16 + r16][g4 * 8]);
#pragma unroll
    for (int i = 0; i < 4; ++i)
#pragma unroll
      for (int j = 0; j < 4; ++j)
        acc[i][j] = __builtin_amdgcn_mfma_f32_16x16x32_bf16(af[i], bfr[j], acc[i][j], 0, 0, 0);
    __syncthreads();
  }
#pragma unroll
  for (int i = 0; i < 4; ++i)
#pragma unroll
    for (int j = 0; j < 4; ++j) {
      int row = m0 + wm * 64 + i * 16 + g4 * 4;
      int col = n0 + wn * 64 + j * 16 + r16;
      float bv = bias[col];
#pragma unroll
      for (int q = 0; q < 4; ++q)
        C[(size_t)(row + q) * 1024 + col] = acc[i][j][q] + bv;
    }
}

extern "C" void kernel_launch(void* const* d_in, const int* in_sizes, int n_in,
                              void* d_out, int out_size, void* d_ws, size_t ws_size,
                              hipStream_t stream) {
  const float* x      = (const float*)d_in[0];
  const float* W_attn = (const float*)d_in[1];
  const float* b_attn = (const float*)d_in[2];
  const float* W_proj = (const float*)d_in[3];
  const float* b_proj = (const float*)d_in[4];
  const float* E      = (const float*)d_in[5];
  const float* F      = (const float*)d_in[6];
  float* out = (float*)d_out;

  char* ws = (char*)d_ws;
  short* xb  = (short*)(ws + 0);          //  32 MB: x bf16            (16384x1024)
  short* WaT = (short*)(ws + 33554432);   //   6 MB: W_attn^T bf16     (3072x1024)
  short* WpT = (short*)(ws + 39845888);   //   2 MB: W_proj^T bf16     (1024x1024)
  short* Et  = (short*)(ws + 41943040);   //   8 MB: E^T bf16          (1024x4096)
  short* Ft  = (short*)(ws + 50331648);   //   8 MB: F^T bf16          (1024x4096)
  short* qb  = (short*)(ws + 58720256);   //  32 MB: q bf16            (16384x1024)
  short* kT  = (short*)(ws + 92274688);   //  32 MB: k^T bf16          (4x1024x4096)
  short* vT  = (short*)(ws + 125829120);  //  32 MB: v^T bf16          (4x1024x4096)
  short* kp  = (short*)(ws + 159383552);  //   8 MB: k_proj bf16       (4x1024x1024)
  short* vpt = (short*)(ws + 167772160);  //   8 MB: v_proj^T bf16     (4x1024x1024)
  short* yb  = (short*)(ws + 176160768);  //  32 MB: attn out bf16     (16384x1024)

  k_convert<<<16384, 256, 0, stream>>>(x, xb, 16777216);
  k_transpose_cvt<<<dim3(96, 32), 256, 0, stream>>>(W_attn, WaT, 1024, 3072);
  k_transpose_cvt<<<dim3(32, 32), 256, 0, stream>>>(W_proj, WpT, 1024, 1024);
  k_transpose_cvt<<<dim3(32, 128), 256, 0, stream>>>(E, Et, 4096, 1024);
  k_transpose_cvt<<<dim3(32, 128), 256, 0, stream>>>(F, Ft, 4096, 1024);

  k_gemm_qkv<<<768, 512, 0, stream>>>(xb, WaT, b_attn, qb, kT, vT);
  k_proj<<<dim3(8, 8, 8), 256, 0, stream>>>(Et, Ft, kT, vT, kp, vpt);
  k_attn<<<dim3(32, 64), 256, 0, stream>>>(qb, kp, vpt, yb);
  k_gemm_out<<<dim3(128, 8), 256, 0, stream>>>(yb, WpT, b_proj, out);
}

// Round 7
// 429.579 us; speedup vs baseline: 1.5441x; 1.0272x over previous
//
#include <hip/hip_runtime.h>
#include <stdint.h>

typedef short bf16x8 __attribute__((ext_vector_type(8)));
typedef short bf16x4 __attribute__((ext_vector_type(4)));
typedef float f32x4 __attribute__((ext_vector_type(4)));
typedef float f32x16 __attribute__((ext_vector_type(16)));
typedef int i32x4 __attribute__((ext_vector_type(4)));

__device__ __forceinline__ short f2bf(float f) {
  union { float f; uint32_t u; } v; v.f = f;
  uint32_t r = (v.u + 0x7FFFu + ((v.u >> 16) & 1u)) >> 16;
  return (short)(uint16_t)r;
}

__device__ __forceinline__ int cvtpk(float lo, float hi) {
  int r;
  asm("v_cvt_pk_bf16_f32 %0, %1, %2" : "=v"(r) : "v"(lo), "v"(hi));
  return r;
}

// async global->LDS, 16B per lane; LDS dest must be linear in lane order
__device__ __forceinline__ void gload16(const void* g, void* l) {
  __builtin_amdgcn_global_load_lds(
      (const __attribute__((address_space(1))) unsigned int*)g,
      (__attribute__((address_space(3))) unsigned int*)l, 16, 0, 0);
}

#define WAITV(n) asm volatile("s_waitcnt vmcnt(" #n ")" ::: "memory")
#define BARRIER()                          \
  do {                                     \
    __builtin_amdgcn_s_barrier();          \
    asm volatile("" ::: "memory");         \
  } while (0)

// ---------------- elementwise f32 -> bf16 ----------------
__global__ __launch_bounds__(256) void k_convert(const float* __restrict__ in,
                                                 short* __restrict__ out, int n) {
  int i = (blockIdx.x * 256 + threadIdx.x) * 4;
  if (i >= n) return;
  float4 v = *reinterpret_cast<const float4*>(in + i);
  bf16x4 o; o[0] = f2bf(v.x); o[1] = f2bf(v.y); o[2] = f2bf(v.z); o[3] = f2bf(v.w);
  *reinterpret_cast<bf16x4*>(out + i) = o;
}

// ---------------- transpose + convert: out[C][R] = bf16(in[R][C]) ----------------
__global__ __launch_bounds__(256) void k_transpose_cvt(const float* __restrict__ in,
                                                       short* __restrict__ out,
                                                       int R, int C) {
  __shared__ float tile[32][33];
  int r0 = blockIdx.y * 32, c0 = blockIdx.x * 32;
  int tx = threadIdx.x & 31, ty = threadIdx.x >> 5;
#pragma unroll
  for (int j = 0; j < 4; ++j)
    tile[ty + j * 8][tx] = in[(size_t)(r0 + ty + j * 8) * C + c0 + tx];
  __syncthreads();
#pragma unroll
  for (int j = 0; j < 4; ++j)
    out[(size_t)(c0 + ty + j * 8) * R + r0 + tx] = f2bf(tile[tx][ty + j * 8]);
}

// ---------------- GEMM1: qkv = x @ W_attn + b  (256x256, BK=32, quad-buffered) --------
// LDS swizzle (rows are 64B = 4 slots of 16B): phys slot s of row r holds logical
// slot s ^ (r&3); gload_lds dest linear, inverse swizzle on GLOBAL source (rule 21).
__global__ __launch_bounds__(512, 2) void k_gemm_qkv(const short* __restrict__ A,
                                                     const short* __restrict__ BT,
                                                     const float* __restrict__ bias,
                                                     short* __restrict__ qb,
                                                     short* __restrict__ kT,
                                                     short* __restrict__ vT) {
  __shared__ __align__(16) char lds[4 * 32768];   // buf b: A @ b*32768, B @ +16384
  const int tid = threadIdx.x, l = tid & 63, wv = tid >> 6;
  const int wm = wv >> 2, wn = wv & 3;            // 2(M) x 4(N), per-wave 128x64
  const int r16 = l & 15, g4 = l >> 4;
  const int orig = blockIdx.x;                    // bijective XCD swizzle (768 = 8*96)
  const int wg = (orig & 7) * 96 + (orig >> 3);
  const int m0 = (wg & 63) * 256, n0 = (wg >> 6) * 256;
  // staging: per tile 4 loads/thread (2 A + 2 B); load i covers rows i*128 + tid/4
  const int sl = (tid & 3) ^ ((tid >> 2) & 3);    // inverse-swizzled source slot
  const short* aS = A + (size_t)(m0 + (tid >> 2)) * 1024 + sl * 8;
  const short* bS = BT + (size_t)(n0 + (tid >> 2)) * 1024 + sl * 8;
  const int sw = (g4 ^ (r16 & 3)) * 16;           // read-side swizzled slot byte

  f32x4 acc[8][4];
#pragma unroll
  for (int i = 0; i < 8; ++i)
#pragma unroll
    for (int j = 0; j < 4; ++j) acc[i][j] = f32x4{0.f, 0.f, 0.f, 0.f};

#define STAGE1(kt, bf)                                                      \
  {                                                                         \
    const int k0_ = (kt) * 32;                                              \
    gload16(aS + k0_, lds + (bf) * 32768 + tid * 16);                       \
    gload16(aS + 131072 + k0_, lds + (bf) * 32768 + 8192 + tid * 16);       \
    gload16(bS + k0_, lds + (bf) * 32768 + 16384 + tid * 16);               \
    gload16(bS + 131072 + k0_, lds + (bf) * 32768 + 24576 + tid * 16);      \
  }

  STAGE1(0, 0); STAGE1(1, 1); STAGE1(2, 2);

  for (int kt = 0; kt < 32; ++kt) {
    if (kt < 30) WAITV(8);
    else if (kt == 30) WAITV(4);
    else WAITV(0);
    BARRIER();
    if (kt + 3 < 32) STAGE1(kt + 3, (kt + 3) & 3);
    const char* aT = lds + (kt & 3) * 32768;
    const char* bT = aT + 16384;
    bf16x8 af[8], bfr[4];
#pragma unroll
    for (int mi = 0; mi < 8; ++mi)
      af[mi] = *(const bf16x8*)(aT + (wm * 128 + mi * 16 + r16) * 64 + sw);
#pragma unroll
    for (int ni = 0; ni < 4; ++ni)
      bfr[ni] = *(const bf16x8*)(bT + (wn * 64 + ni * 16 + r16) * 64 + sw);
    __builtin_amdgcn_s_setprio(1);
#pragma unroll
    for (int mi = 0; mi < 8; ++mi)
#pragma unroll
      for (int ni = 0; ni < 4; ++ni)
        acc[mi][ni] = __builtin_amdgcn_mfma_f32_16x16x32_bf16(af[mi], bfr[ni], acc[mi][ni], 0, 0, 0);
    __builtin_amdgcn_s_setprio(0);
  }
#undef STAGE1

  const int seg = n0 >> 10;  // 0=q, 1=k, 2=v (256-col tiles never straddle)
#pragma unroll
  for (int i = 0; i < 8; ++i)
#pragma unroll
    for (int j = 0; j < 4; ++j) {
      int row = m0 + wm * 128 + i * 16 + g4 * 4;
      int colg = n0 + wn * 64 + j * 16 + r16;
      float bv = bias[colg];
      if (seg == 0) {
#pragma unroll
        for (int q = 0; q < 4; ++q)
          qb[(size_t)(row + q) * 1024 + colg] = f2bf(acc[i][j][q] + bv);
      } else {
        int c = colg & 1023;
        int bb = row >> 12, t = row & 4095;
        short* dst = (seg == 1) ? kT : vT;
        bf16x4 ov;
#pragma unroll
        for (int q = 0; q < 4; ++q) ov[q] = f2bf(acc[i][j][q] + bv);
        *reinterpret_cast<bf16x4*>(&dst[((size_t)(bb << 10) + c) * 4096 + t]) = ov;
      }
    }
}

// ---------------- Projection (128x128, BK=32, quad-buffered, nt=128) ----------------
// which=0: kp[b][kk][c] = (sum_t Et[kk][t]*kT[b][c][t]) / 8
// which=1: vpt[b][c][kk] = sum_t Ft[kk][t]*vT[b][c][t]   (transposed store)
__global__ __launch_bounds__(256, 2) void k_proj(const short* __restrict__ Et,
                                                 const short* __restrict__ Ft,
                                                 const short* __restrict__ kT,
                                                 const short* __restrict__ vT,
                                                 short* __restrict__ kp,
                                                 short* __restrict__ vpt) {
  const int z = blockIdx.z, b = z >> 1, which = z & 1;
  const short* __restrict__ AT = which ? Ft : Et;
  const short* __restrict__ BTp = (which ? vT : kT) + ((size_t)b << 10) * 4096;
  __shared__ __align__(16) char lds[4 * 16384];   // buf: A @ b*16384, B @ +8192
  const int tid = threadIdx.x, l = tid & 63, wv = tid >> 6;
  const int wm = wv >> 1, wn = wv & 1;            // 2x2 waves, per-wave 64x64
  const int r16 = l & 15, g4 = l >> 4;
  const int m0 = blockIdx.x * 128, n0 = blockIdx.y * 128;
  const int sl = (tid & 3) ^ ((tid >> 2) & 3);
  const short* aS = AT + (size_t)(m0 + (tid >> 2)) * 4096 + sl * 8;
  const short* bS = BTp + (size_t)(n0 + (tid >> 2)) * 4096 + sl * 8;
  const int sw = (g4 ^ (r16 & 3)) * 16;

  f32x4 acc[4][4];
#pragma unroll
  for (int i = 0; i < 4; ++i)
#pragma unroll
    for (int j = 0; j < 4; ++j) acc[i][j] = f32x4{0.f, 0.f, 0.f, 0.f};

#define STAGE2(kt, bf)                                                      \
  {                                                                         \
    const int k0_ = (kt) * 32;                                              \
    gload16(aS + k0_, lds + (bf) * 16384 + tid * 16);                       \
    gload16(aS + 262144 + k0_, lds + (bf) * 16384 + 4096 + tid * 16);       \
    gload16(bS + k0_, lds + (bf) * 16384 + 8192 + tid * 16);                \
    gload16(bS + 262144 + k0_, lds + (bf) * 16384 + 12288 + tid * 16);      \
  }

  STAGE2(0, 0); STAGE2(1, 1); STAGE2(2, 2);

  for (int kt = 0; kt < 128; ++kt) {
    if (kt < 126) WAITV(8);
    else if (kt == 126) WAITV(4);
    else WAITV(0);
    BARRIER();
    if (kt + 3 < 128) STAGE2(kt + 3, (kt + 3) & 3);
    const char* aT = lds + (kt & 3) * 16384;
    const char* bT = aT + 8192;
    bf16x8 af[4], bfr[4];
#pragma unroll
    for (int mi = 0; mi < 4; ++mi)
      af[mi] = *(const bf16x8*)(aT + (wm * 64 + mi * 16 + r16) * 64 + sw);
#pragma unroll
    for (int ni = 0; ni < 4; ++ni)
      bfr[ni] = *(const bf16x8*)(bT + (wn * 64 + ni * 16 + r16) * 64 + sw);
    __builtin_amdgcn_s_setprio(1);
#pragma unroll
    for (int mi = 0; mi < 4; ++mi)
#pragma unroll
      for (int ni = 0; ni < 4; ++ni)
        acc[mi][ni] = __builtin_amdgcn_mfma_f32_16x16x32_bf16(af[mi], bfr[ni], acc[mi][ni], 0, 0, 0);
    __builtin_amdgcn_s_setprio(0);
  }
#undef STAGE2

  if (which) {
#pragma unroll
    for (int i = 0; i < 4; ++i)
#pragma unroll
      for (int j = 0; j < 4; ++j) {
        int row = m0 + wm * 64 + i * 16 + g4 * 4;   // kk
        int col = n0 + wn * 64 + j * 16 + r16;      // c
        bf16x4 ov;
#pragma unroll
        for (int q = 0; q < 4; ++q) ov[q] = f2bf(acc[i][j][q]);
        *reinterpret_cast<bf16x4*>(&vpt[((size_t)(b * 1024) + col) * 1024 + row]) = ov;
      }
  } else {
#pragma unroll
    for (int i = 0; i < 4; ++i)
#pragma unroll
      for (int j = 0; j < 4; ++j) {
        int row = m0 + wm * 64 + i * 16 + g4 * 4;
        int col = n0 + wn * 64 + j * 16 + r16;
#pragma unroll
        for (int q = 0; q < 4; ++q)
          kp[((size_t)(b * 1024) + row + q) * 1024 + col] = f2bf(acc[i][j][q] * 0.125f);
      }
  }
}

// ---------------- Flash attention: swapped 32x32x16 MFMA, in-register P ----------------
__global__ __launch_bounds__(256, 3) void k_attn(const short* __restrict__ qb,
                                                 const short* __restrict__ kp,
                                                 const short* __restrict__ vpt,
                                                 short* __restrict__ y) {
  __shared__ __align__(16) char KsB[128 * 128];   // [kk][d] swizzled, 16 KB
  __shared__ __align__(16) char VtB[64 * 256];    // [d][kk] swizzled, 16 KB
  const int tid = threadIdx.x, lane = tid & 63, w = tid >> 6;
  const int r32 = lane & 31, hi = lane >> 5;
  const int iblk = blockIdx.x;
  const int bh = blockIdx.y, b = bh >> 4, h = bh & 15;
  const int t0 = iblk * 128;
  const int tl = w * 32 + r32;          // local row
  const int T = t0 + tl;                // global row (within b)

  bf16x8 qf[4];
#pragma unroll
  for (int kd = 0; kd < 4; ++kd)
    qf[kd] = *reinterpret_cast<const bf16x8*>(
        &qb[(size_t)(b * 4096 + T) * 1024 + h * 64 + kd * 16 + hi * 8]);

  f32x16 o[2];
#pragma unroll
  for (int i = 0; i < 16; ++i) { o[0][i] = 0.f; o[1][i] = 0.f; }
  float mrun = -1e30f, lrun = 0.f;

  const short* kpb = kp + ((size_t)b << 20) + h * 64;             // [kk][c]
  const short* vtb = vpt + (((size_t)b << 10) + h * 64) * 1024;   // [c][kk]

  const int ntiles = (iblk + 1 < 8) ? (iblk + 1) : 8;
  for (int jt = 0; jt < ntiles; ++jt) {
    const int kk0 = jt * 128;
    __syncthreads();
#pragma unroll
    for (int it = 0; it < 4; ++it) {
      int slot = tid + it * 256;
      int kk = slot >> 3, c8 = slot & 7;
      bf16x8 kv = *reinterpret_cast<const bf16x8*>(&kpb[(size_t)(kk0 + kk) * 1024 + c8 * 8]);
      *reinterpret_cast<bf16x8*>(&KsB[kk * 128 + ((c8 * 16) ^ ((kk & 7) << 4))]) = kv;
      int d = slot >> 4, c16 = slot & 15;
      bf16x8 vv = *reinterpret_cast<const bf16x8*>(&vtb[(size_t)d * 1024 + kk0 + c16 * 8]);
      *reinterpret_cast<bf16x8*>(&VtB[d * 256 + ((c16 * 16) ^ ((d & 7) << 4))]) = vv;
    }
    __syncthreads();

#pragma unroll
    for (int st = 0; st < 2; ++st) {          // 64-kk sub-tiles
      f32x16 s[2];
#pragma unroll
      for (int i = 0; i < 16; ++i) { s[0][i] = 0.f; s[1][i] = 0.f; }
#pragma unroll
      for (int ni = 0; ni < 2; ++ni) {
        int n = st * 2 + ni;
#pragma unroll
        for (int kd = 0; kd < 4; ++kd) {
          int row = n * 32 + r32;
          bf16x8 kf = *reinterpret_cast<const bf16x8*>(
              &KsB[row * 128 + ((kd * 32 + hi * 16) ^ ((row & 7) << 4))]);
          s[ni] = __builtin_amdgcn_mfma_f32_32x32x16_bf16(kf, qf[kd], s[ni], 0, 0, 0);
        }
      }

      if (jt == iblk) {  // causal mask on diagonal tile
#pragma unroll
        for (int ni = 0; ni < 2; ++ni)
#pragma unroll
          for (int j = 0; j < 16; ++j) {
            int kkl = (st * 2 + ni) * 32 + (j & 3) + 8 * (j >> 2) + 4 * hi;
            if (kkl > tl) s[ni][j] = -1e30f;
          }
      }

      float pmax = s[0][0];
#pragma unroll
      for (int j = 1; j < 16; ++j) pmax = fmaxf(pmax, s[0][j]);
#pragma unroll
      for (int j = 0; j < 16; ++j) pmax = fmaxf(pmax, s[1][j]);
      pmax = fmaxf(pmax, __shfl_xor(pmax, 32, 64));
      float newm = fmaxf(mrun, pmax);
      float corr = __expf(mrun - newm);
      mrun = newm;
      float rsum = 0.f;
#pragma unroll
      for (int ni = 0; ni < 2; ++ni)
#pragma unroll
        for (int j = 0; j < 16; ++j) {
          float pv = __expf(s[ni][j] - newm);
          s[ni][j] = pv;
          rsum += pv;
        }
      rsum += __shfl_xor(rsum, 32, 64);
      lrun = lrun * corr + rsum;
#pragma unroll
      for (int i = 0; i < 16; ++i) { o[0][i] *= corr; o[1][i] *= corr; }

#pragma unroll
      for (int kbl = 0; kbl < 4; ++kbl) {
        const int ni = kbl >> 1, jb = (kbl & 1) * 8;
        int lo0 = cvtpk(s[ni][jb + 0], s[ni][jb + 1]);
        int lo1 = cvtpk(s[ni][jb + 2], s[ni][jb + 3]);
        int hi0 = cvtpk(s[ni][jb + 4], s[ni][jb + 5]);
        int hi1 = cvtpk(s[ni][jb + 6], s[ni][jb + 7]);
        asm("v_permlane32_swap_b32 %0, %1" : "+v"(lo0), "+v"(hi0));
        asm("v_permlane32_swap_b32 %0, %1" : "+v"(lo1), "+v"(hi1));
        i32x4 pw; pw[0] = lo0; pw[1] = lo1; pw[2] = hi0; pw[3] = hi1;
        bf16x8 pf = __builtin_bit_cast(bf16x8, pw);
        const int kb = st * 4 + kbl;
#pragma unroll
        for (int mo = 0; mo < 2; ++mo) {
          int row = mo * 32 + r32;
          bf16x8 vf = *reinterpret_cast<const bf16x8*>(
              &VtB[row * 256 + ((kb * 32 + hi * 16) ^ ((row & 7) << 4))]);
          o[mo] = __builtin_amdgcn_mfma_f32_32x32x16_bf16(vf, pf, o[mo], 0, 0, 0);
        }
      }
    }
  }

  float inv = 1.0f / lrun;
#pragma unroll
  for (int mo = 0; mo < 2; ++mo)
#pragma unroll
    for (int rq = 0; rq < 4; ++rq) {
      bf16x4 ov;
#pragma unroll
      for (int c = 0; c < 4; ++c) ov[c] = f2bf(o[mo][rq * 4 + c] * inv);
      *reinterpret_cast<bf16x4*>(
          &y[(size_t)(b * 4096 + T) * 1024 + h * 64 + mo * 32 + rq * 8 + hi * 4]) = ov;
    }
}

// ---------------- GEMM2: out = y @ W_proj + b (128x128, BK=32, quad-buffered) --------
__global__ __launch_bounds__(256, 2) void k_gemm_out(const short* __restrict__ A,
                                                     const short* __restrict__ BT,
                                                     const float* __restrict__ bias,
                                                     float* __restrict__ C) {
  __shared__ __align__(16) char lds[4 * 16384];
  const int tid = threadIdx.x, l = tid & 63, wv = tid >> 6;
  const int wm = wv >> 1, wn = wv & 1;
  const int r16 = l & 15, g4 = l >> 4;
  const int m0 = blockIdx.x * 128, n0 = blockIdx.y * 128;
  const int sl = (tid & 3) ^ ((tid >> 2) & 3);
  const short* aS = A + (size_t)(m0 + (tid >> 2)) * 1024 + sl * 8;
  const short* bS = BT + (size_t)(n0 + (tid >> 2)) * 1024 + sl * 8;
  const int sw = (g4 ^ (r16 & 3)) * 16;

  f32x4 acc[4][4];
#pragma unroll
  for (int i = 0; i < 4; ++i)
#pragma unroll
    for (int j = 0; j < 4; ++j) acc[i][j] = f32x4{0.f, 0.f, 0.f, 0.f};

#define STAGE3(kt, bf)                                                      \
  {                                                                         \
    const int k0_ = (kt) * 32;                                              \
    gload16(aS + k0_, lds + (bf) * 16384 + tid * 16);                       \
    gload16(aS + 65536 + k0_, lds + (bf) * 16384 + 4096 + tid * 16);        \
    gload16(bS + k0_, lds + (bf) * 16384 + 8192 + tid * 16);                \
    gload16(bS + 65536 + k0_, lds + (bf) * 16384 + 12288 + tid * 16);       \
  }

  STAGE3(0, 0); STAGE3(1, 1); STAGE3(2, 2);

  for (int kt = 0; kt < 32; ++kt) {
    if (kt < 30) WAITV(8);
    else if (kt == 30) WAITV(4);
    else WAITV(0);
    BARRIER();
    if (kt + 3 < 32) STAGE3(kt + 3, (kt + 3) & 3);
    const char* aT = lds + (kt & 3) * 16384;
    const char* bT = aT + 8192;
    bf16x8 af[4], bfr[4];
#pragma unroll
    for (int mi = 0; mi < 4; ++mi)
      af[mi] = *(const bf16x8*)(aT + (wm * 64 + mi * 16 + r16) * 64 + sw);
#pragma unroll
    for (int ni = 0; ni < 4; ++ni)
      bfr[ni] = *(const bf16x8*)(bT + (wn * 64 + ni * 16 + r16) * 64 + sw);
    __builtin_amdgcn_s_setprio(1);
#pragma unroll
    for (int mi = 0; mi < 4; ++mi)
#pragma unroll
      for (int ni = 0; ni < 4; ++ni)
        acc[mi][ni] = __builtin_amdgcn_mfma_f32_16x16x32_bf16(af[mi], bfr[ni], acc[mi][ni], 0, 0, 0);
    __builtin_amdgcn_s_setprio(0);
  }
#undef STAGE3

#pragma unroll
  for (int i = 0; i < 4; ++i)
#pragma unroll
    for (int j = 0; j < 4; ++j) {
      int row = m0 + wm * 64 + i * 16 + g4 * 4;
      int col = n0 + wn * 64 + j * 16 + r16;
      float bv = bias[col];
#pragma unroll
      for (int q = 0; q < 4; ++q)
        C[(size_t)(row + q) * 1024 + col] = acc[i][j][q] + bv;
    }
}

extern "C" void kernel_launch(void* const* d_in, const int* in_sizes, int n_in,
                              void* d_out, int out_size, void* d_ws, size_t ws_size,
                              hipStream_t stream) {
  const float* x      = (const float*)d_in[0];
  const float* W_attn = (const float*)d_in[1];
  const float* b_attn = (const float*)d_in[2];
  const float* W_proj = (const float*)d_in[3];
  const float* b_proj = (const float*)d_in[4];
  const float* E      = (const float*)d_in[5];
  const float* F      = (const float*)d_in[6];
  float* out = (float*)d_out;

  char* ws = (char*)d_ws;
  short* xb  = (short*)(ws + 0);          //  32 MB: x bf16            (16384x1024)
  short* WaT = (short*)(ws + 33554432);   //   6 MB: W_attn^T bf16     (3072x1024)
  short* WpT = (short*)(ws + 39845888);   //   2 MB: W_proj^T bf16     (1024x1024)
  short* Et  = (short*)(ws + 41943040);   //   8 MB: E^T bf16          (1024x4096)
  short* Ft  = (short*)(ws + 50331648);   //   8 MB: F^T bf16          (1024x4096)
  short* qb  = (short*)(ws + 58720256);   //  32 MB: q bf16            (16384x1024)
  short* kT  = (short*)(ws + 92274688);   //  32 MB: k^T bf16          (4x1024x4096)
  short* vT  = (short*)(ws + 125829120);  //  32 MB: v^T bf16          (4x1024x4096)
  short* kp  = (short*)(ws + 159383552);  //   8 MB: k_proj bf16       (4x1024x1024)
  short* vpt = (short*)(ws + 167772160);  //   8 MB: v_proj^T bf16     (4x1024x1024)
  short* yb  = (short*)(ws + 176160768);  //  32 MB: attn out bf16     (16384x1024)

  k_convert<<<16384, 256, 0, stream>>>(x, xb, 16777216);
  k_transpose_cvt<<<dim3(96, 32), 256, 0, stream>>>(W_attn, WaT, 1024, 3072);
  k_transpose_cvt<<<dim3(32, 32), 256, 0, stream>>>(W_proj, WpT, 1024, 1024);
  k_transpose_cvt<<<dim3(32, 128), 256, 0, stream>>>(E, Et, 4096, 1024);
  k_transpose_cvt<<<dim3(32, 128), 256, 0, stream>>>(F, Ft, 4096, 1024);

  k_gemm_qkv<<<768, 512, 0, stream>>>(xb, WaT, b_attn, qb, kT, vT);
  k_proj<<<dim3(8, 8, 8), 256, 0, stream>>>(Et, Ft, kT, vT, kp, vpt);
  k_attn<<<dim3(32, 64), 256, 0, stream>>>(qb, kp, vpt, yb);
  k_gemm_out<<<dim3(128, 8), 256, 0, stream>>>(yb, WpT, b_proj, out);
}